// Round 3
// baseline (957.819 us; speedup 1.0000x reference)
//
#include <hip/hip_runtime.h>
#include <hip/hip_bf16.h>

typedef short short8 __attribute__((ext_vector_type(8)));
typedef float f32x4 __attribute__((ext_vector_type(4)));

#define H 512
#define BATCH 64
#define SEQ 256
#define NROWS 16384   // BATCH*SEQ

__device__ __forceinline__ float bf2f(unsigned short u) {
    union { unsigned int i; float f; } v;
    v.i = ((unsigned int)u) << 16;
    return v.f;
}
__device__ __forceinline__ unsigned short f2bf(float f) {
    union { float f; unsigned int i; } v;
    v.f = f;
    unsigned int lsb = (v.i >> 16) & 1u;
    v.i += 0x7fffu + lsb;   // round-to-nearest-even
    return (unsigned short)(v.i >> 16);
}
__device__ __forceinline__ float sigm(float x) { return 1.f / (1.f + __expf(-x)); }
__device__ __forceinline__ float tanh_fast(float x) { return 2.f / (1.f + __expf(-2.f * x)) - 1.f; }

// ---------------------------------------------------------------------------
// convert + init: x->bf16, Wl->bf16, W_ih->bf16; zero meta region
// ---------------------------------------------------------------------------
__global__ __launch_bounds__(256) void cvt_init(
    const float* __restrict__ x, const float* __restrict__ Wl,
    const float* __restrict__ Wih,
    unsigned short* __restrict__ actA, unsigned short* __restrict__ wlb,
    unsigned short* __restrict__ wihb, unsigned int* __restrict__ meta)
{
    long idx4 = (long)blockIdx.x * 256 + threadIdx.x;
    if (idx4 < 1024) meta[idx4] = 0u;
    long i = idx4 * 4;
    const long N1 = 8388608;            // x: 16384*512
    const long N2 = N1 + 1048576;       // Wl: 4*512*512
    const long N3 = N2 + 786432;        // W_ih: 1536*512
    const float* src; unsigned short* dst; long off;
    if (i < N1)      { src = x;   dst = actA; off = i; }
    else if (i < N2) { src = Wl;  dst = wlb;  off = i - N1; }
    else if (i < N3) { src = Wih; dst = wihb; off = i - N2; }
    else return;
    float4 v = *(const float4*)(src + off);
    ushort4 o;
    o.x = f2bf(v.x); o.y = f2bf(v.y); o.z = f2bf(v.z); o.w = f2bf(v.w);
    *(ushort4*)(dst + off) = o;
}

// ---------------------------------------------------------------------------
// Segment machinery. Segment = maximal run starting at s where (s==0 || done[b,s]).
// ---------------------------------------------------------------------------
__global__ __launch_bounds__(256) void seg_build(
    const int* __restrict__ dones, int* __restrict__ lenArr,
    unsigned int* __restrict__ hist)
{
    __shared__ int d[256];
    const int b = blockIdx.x, s = threadIdx.x;
    d[s] = dones[b * 256 + s];
    __syncthreads();
    int len = 0;
    bool start = (s == 0) || (d[s] != 0);
    if (start) {
        len = 1;
        while (s + len < 256 && d[s + len] == 0) len++;
        atomicAdd(&hist[len], 1u);
    }
    lenArr[b * 256 + s] = len;
}

// M[t] = #segments with len > t; offs[L]=M[L] (scatter cursors); ssum = prefix(M)
__global__ __launch_bounds__(256) void seg_offsets(
    const unsigned int* __restrict__ hist, int* __restrict__ Marr,
    unsigned int* __restrict__ offs, unsigned int* __restrict__ ssum)
{
    __shared__ unsigned int h[257];
    __shared__ int Msh[257];
    const int t = threadIdx.x;
    h[t] = hist[t];
    if (t == 0) h[256] = hist[256];
    __syncthreads();
    for (int tt = t; tt <= 256; tt += 256) {
        unsigned int m = 0;
        for (int L = tt + 1; L <= 256; ++L) m += h[L];
        Marr[tt] = (int)m;
        offs[tt] = m;
        Msh[tt] = (int)m;
    }
    __syncthreads();
    if (t == 0) {
        unsigned int acc = 0;
        for (int k = 0; k <= 256; ++k) { ssum[k] = acc; acc += (unsigned int)Msh[k]; }
    }
}

// counting-sort scatter: rows sorted by length descending -> alive set is prefix
__global__ __launch_bounds__(256) void seg_scatter(
    const int* __restrict__ lenArr, unsigned int* __restrict__ offs,
    int* __restrict__ recs)
{
    const int b = blockIdx.x, s = threadIdx.x;
    int len = lenArr[b * 256 + s];
    if (len > 0) {
        unsigned int pos = atomicAdd(&offs[len], 1u);
        recs[pos] = (b << 16) | s;
    }
}

// pmap[(b,s)] = ssum[t] + rank : gi GEMM output row permutation
__global__ __launch_bounds__(256) void pmap_build(
    const int* __restrict__ recs, const int* __restrict__ Marr,
    const unsigned int* __restrict__ ssum, const int* __restrict__ lenArr,
    int* __restrict__ pmap)
{
    const int i = blockIdx.x * 256 + threadIdx.x;
    if (i >= Marr[0]) return;
    int rec = recs[i];
    int b = rec >> 16, st = rec & 0xffff;
    int len = lenArr[b * 256 + st];
    for (int t = 0; t < len; ++t) pmap[b * 256 + st + t] = (int)ssum[t] + i;
}

// h_state row init by rank: hidden[b] for the s==0 segment when !done[b,0], else 0.
__global__ __launch_bounds__(256) void h_init(
    const int* __restrict__ recs, const int* __restrict__ Marr,
    const int* __restrict__ dones, const float* __restrict__ hidden,
    unsigned short* __restrict__ hst)
{
    const int w = threadIdx.x >> 6, lane = threadIdx.x & 63;
    const int i = blockIdx.x * 4 + w;
    const int nseg = Marr[0];
    const int c0 = lane * 8;
    unsigned short* dst = hst + (long)i * 512 + c0;
    if (i < nseg) {
        int rec = recs[i];
        int b = rec >> 16, st = rec & 0xffff;
        if (st == 0 && dones[b * 256] == 0) {
            float4 va = *(const float4*)(hidden + b * 512 + c0);
            float4 vb = *(const float4*)(hidden + b * 512 + c0 + 4);
            ushort4 o0 = {f2bf(va.x), f2bf(va.y), f2bf(va.z), f2bf(va.w)};
            ushort4 o1 = {f2bf(vb.x), f2bf(vb.y), f2bf(vb.z), f2bf(vb.w)};
            *(ushort4*)dst = o0; *(ushort4*)(dst + 4) = o1;
            return;
        }
    }
    ushort4 z4 = {0, 0, 0, 0};
    *(ushort4*)dst = z4; *(ushort4*)(dst + 4) = z4;
}

// ---------------------------------------------------------------------------
// GEMM: C[M,N] = A[M,K](bf16) * Bw[N,K]^T(bf16) + bias[N]; optional row remap
// ---------------------------------------------------------------------------
template <int BF16OUT>
__global__ __launch_bounds__(256) void gemm_bt(
    const unsigned short* __restrict__ A, const unsigned short* __restrict__ Bw,
    const float* __restrict__ bias, void* __restrict__ Cout,
    int M, int N, int K, const int* __restrict__ rowmap)
{
    __shared__ unsigned short ldsA[128 * 64];
    __shared__ unsigned short ldsB[128 * 64];
    const int tid = threadIdx.x;
    const int lane = tid & 63;
    const int w = tid >> 6;
    const int nbx = N >> 7;
    const int bm = blockIdx.x / nbx;
    const int bn = blockIdx.x % nbx;
    const long m0 = (long)bm * 128;
    const long n0 = (long)bn * 128;
    const long Kb = (long)K * 2;

    f32x4 acc[4][4];
#pragma unroll
    for (int i = 0; i < 4; ++i)
#pragma unroll
        for (int j = 0; j < 4; ++j) acc[i][j] = (f32x4){0.f, 0.f, 0.f, 0.f};

    for (int kt = 0; kt < K; kt += 64) {
        __syncthreads();
#pragma unroll
        for (int i = 0; i < 4; ++i) {
            int o   = (i * 256 + tid) * 16;
            int row = o >> 7;
            int ch  = (o & 127) >> 4;
            long gcol = (long)kt * 2 + (long)((ch ^ (row & 7)) << 4);
            int ldsoff = (i * 256 + w * 64) * 8;
            __builtin_amdgcn_global_load_lds(
                (const unsigned int*)((const char*)A + (m0 + row) * Kb + gcol),
                (unsigned int*)(ldsA + ldsoff), 16, 0, 0);
            __builtin_amdgcn_global_load_lds(
                (const unsigned int*)((const char*)Bw + (n0 + row) * Kb + gcol),
                (unsigned int*)(ldsB + ldsoff), 16, 0, 0);
        }
        __syncthreads();

#pragma unroll
        for (int k2 = 0; k2 < 2; ++k2) {
            short8 af[4], bfr[4];
#pragma unroll
            for (int i = 0; i < 4; ++i) {
                int row = (w >> 1) * 64 + i * 16 + (lane & 15);
                int byteo = (row * 128 + k2 * 64 + ((lane >> 4) * 16)) ^ ((row & 7) << 4);
                af[i] = *(const short8*)((const char*)ldsA + byteo);
            }
#pragma unroll
            for (int j = 0; j < 4; ++j) {
                int row = (w & 1) * 64 + j * 16 + (lane & 15);
                int byteo = (row * 128 + k2 * 64 + ((lane >> 4) * 16)) ^ ((row & 7) << 4);
                bfr[j] = *(const short8*)((const char*)ldsB + byteo);
            }
#pragma unroll
            for (int i = 0; i < 4; ++i)
#pragma unroll
                for (int j = 0; j < 4; ++j)
                    acc[i][j] = __builtin_amdgcn_mfma_f32_16x16x32_bf16(af[i], bfr[j], acc[i][j], 0, 0, 0);
        }
    }

#pragma unroll
    for (int j = 0; j < 4; ++j) {
        long n = n0 + (w & 1) * 64 + j * 16 + (lane & 15);
        float bz = bias ? bias[n] : 0.f;
#pragma unroll
        for (int i = 0; i < 4; ++i) {
#pragma unroll
            for (int r = 0; r < 4; ++r) {
                long m = m0 + (w >> 1) * 64 + i * 16 + (lane >> 4) * 4 + r;
                long mm = rowmap ? (long)rowmap[m] : m;
                float v = acc[i][j][r] + bz;
                if (BF16OUT) ((unsigned short*)Cout)[mm * N + n] = f2bf(v);
                else         ((float*)Cout)[mm * N + n] = v;
            }
        }
    }
}

// ---------------------------------------------------------------------------
// LayerNorm + ReLU (unchanged)
// ---------------------------------------------------------------------------
__global__ __launch_bounds__(256) void ln_relu(
    const float* __restrict__ X, const float* __restrict__ g,
    const float* __restrict__ b, unsigned short* __restrict__ Y)
{
    const int w = threadIdx.x >> 6;
    const int lane = threadIdx.x & 63;
    const long row = (long)blockIdx.x * 4 + w;
    const float* xr = X + row * H;
    float4 v0 = *(const float4*)(xr + lane * 4);
    float4 v1 = *(const float4*)(xr + 256 + lane * 4);
    float s = v0.x + v0.y + v0.z + v0.w + v1.x + v1.y + v1.z + v1.w;
    float q = v0.x * v0.x + v0.y * v0.y + v0.z * v0.z + v0.w * v0.w
            + v1.x * v1.x + v1.y * v1.y + v1.z * v1.z + v1.w * v1.w;
#pragma unroll
    for (int off = 1; off < 64; off <<= 1) {
        s += __shfl_xor(s, off);
        q += __shfl_xor(q, off);
    }
    float mu = s * (1.f / 512.f);
    float var = q * (1.f / 512.f) - mu * mu;
    float rs = rsqrtf(var + 1e-5f);
    int c0 = lane * 4;
    float4 ga = *(const float4*)(g + c0);
    float4 ba = *(const float4*)(b + c0);
    float4 gb = *(const float4*)(g + 256 + c0);
    float4 bb = *(const float4*)(b + 256 + c0);
    ushort4 o0, o1;
    o0.x = f2bf(fmaxf(0.f, (v0.x - mu) * rs * ga.x + ba.x));
    o0.y = f2bf(fmaxf(0.f, (v0.y - mu) * rs * ga.y + ba.y));
    o0.z = f2bf(fmaxf(0.f, (v0.z - mu) * rs * ga.z + ba.z));
    o0.w = f2bf(fmaxf(0.f, (v0.w - mu) * rs * ga.w + ba.w));
    o1.x = f2bf(fmaxf(0.f, (v1.x - mu) * rs * gb.x + bb.x));
    o1.y = f2bf(fmaxf(0.f, (v1.y - mu) * rs * gb.y + bb.y));
    o1.z = f2bf(fmaxf(0.f, (v1.z - mu) * rs * gb.z + bb.z));
    o1.w = f2bf(fmaxf(0.f, (v1.w - mu) * rs * gb.w + bb.w));
    *(ushort4*)(Y + row * H + c0) = o0;
    *(ushort4*)(Y + row * H + 256 + c0) = o1;
}

// ---------------------------------------------------------------------------
// 2-level grid barrier: 8 groups x 32 WGs. meta[0..7] group ctrs, meta[8] root,
// meta[9] release flag. Epoch-monotone counters (proven in r1/r2).
// ---------------------------------------------------------------------------
__device__ __forceinline__ void gbar(unsigned int* __restrict__ meta,
                                     int gid, unsigned int epoch)
{
    __syncthreads();
    if (threadIdx.x == 0) {
        unsigned int p = __hip_atomic_fetch_add(&meta[gid], 1u, __ATOMIC_ACQ_REL,
                                                __HIP_MEMORY_SCOPE_AGENT);
        bool release = false;
        if (p == (epoch + 1u) * 32u - 1u) {
            unsigned int q = __hip_atomic_fetch_add(&meta[8], 1u, __ATOMIC_ACQ_REL,
                                                    __HIP_MEMORY_SCOPE_AGENT);
            if (q == (epoch + 1u) * 8u - 1u) {
                __hip_atomic_store(&meta[9], epoch + 1u, __ATOMIC_RELEASE,
                                   __HIP_MEMORY_SCOPE_AGENT);
                release = true;
            }
        }
        if (!release) {
            while (__hip_atomic_load(&meta[9], __ATOMIC_ACQUIRE,
                                     __HIP_MEMORY_SCOPE_AGENT) <= epoch)
                __builtin_amdgcn_s_sleep(2);
        }
    }
    __syncthreads();
}

// ---------------------------------------------------------------------------
// Segment-parallel GRU scan, XCD-colocated + register-pipelined.
// Grid 256 = 32 jg (j-slice, W_hh 48 rows in LDS) x 8 rgrp (= blockIdx%8 = XCD).
// Tile tt (64 ranks) owned by rgrp = tt%8 forever -> h traffic stays in XCD L2.
// Pipeline: h-rows(i+1) global->regs during compute(i); gi/recs(i+1) after
// pointwise(i). Two syncthreads per tile, no global_load_lds drain stalls.
// ---------------------------------------------------------------------------
__global__ __launch_bounds__(256, 1) void gru_seg_scan(
    const unsigned short* __restrict__ gi,   // [16384,1536] bf16, row-permuted
    const float* __restrict__ Whh,           // [1536,512] f32
    const float* __restrict__ bhh,           // [1536] f32
    const int* __restrict__ Marr,
    const unsigned int* __restrict__ ssum,
    const int* __restrict__ recs,
    unsigned short* __restrict__ hstA,       // by rank, read when t even
    unsigned short* __restrict__ hstB,
    unsigned short* __restrict__ rnn,        // [B*S,512] bf16
    float* __restrict__ hid_out,             // [64,512] f32
    unsigned int* __restrict__ meta)
{
    __shared__ unsigned short ldsW[48 * 512];   // 48 KB
    __shared__ unsigned short ldsA[64 * 512];   // 64 KB
    const int tid = threadIdx.x;
    const int lane = tid & 63;
    const int w = tid >> 6;
    const int jg = blockIdx.x >> 3;
    const int rgrp = blockIdx.x & 7;            // = XCD (round-robin %8)
    const int j0 = jg * 16;

    // stage W_hh slice (rows: r gate j0..+15, z, n), f32 -> bf16, XOR swizzle
    for (int e = tid; e < 48 * 512; e += 256) {
        int rrow = e >> 9;
        int col = e & 511;
        int gate = rrow >> 4;
        int jl = rrow & 15;
        float v = Whh[((long)(gate * 512 + j0 + jl)) * 512 + col];
        int byteo = (rrow * 1024 + col * 2) ^ ((rrow & 7) << 4);
        *(unsigned short*)((char*)ldsW + byteo) = f2bf(v);
    }

    const int j = j0 + (lane & 15);
    const float bhr = bhh[j];
    const float bhz = bhh[512 + j];
    const float bhn = bhh[1024 + j];
    const int rbase = w * 16 + (lane >> 4) * 4;   // pointwise row base (local)
    __syncthreads();

    uint4 hreg[16];
    unsigned short gr[4], gz[4], gn[4];
    int rec4[4];

    for (int t = 0; t < 256; ++t) {
        const int Mt = Marr[t];
        if (Mt == 0) break;
        const long base = (long)ssum[t];
        const unsigned short* hsrc = (t & 1) ? hstB : hstA;
        unsigned short* hdst = (t & 1) ? hstA : hstB;
        const int ntiles = (Mt + 63) >> 6;

        int tt = rgrp;
        if (tt < ntiles) {
            // prologue: issue loads for first tile
            const char* hb = (const char*)hsrc + ((long)tt * 64) * 1024;
#pragma unroll
            for (int l = 0; l < 16; ++l)
                hreg[l] = *(const uint4*)(hb + (l * 4 + w) * 1024 + lane * 16);
#pragma unroll
            for (int q = 0; q < 4; ++q) {
                int r = tt * 64 + rbase + q;
                if (r < Mt) {
                    rec4[q] = recs[r];
                    const unsigned short* gp = gi + (base + r) * 1536 + j;
                    gr[q] = gp[0]; gz[q] = gp[512]; gn[q] = gp[1024];
                } else rec4[q] = -1;
            }
        }

        for (; tt < ntiles; tt += 8) {
            const int ttn = tt + 8;
            __syncthreads();   // (a) all waves done reading ldsA

            // write tile i h-rows into swizzled ldsA
#pragma unroll
            for (int l = 0; l < 16; ++l) {
                int row = l * 4 + w;
                int byteo = (row * 1024 + lane * 16) ^ ((row & 7) << 4);
                *(uint4*)((char*)ldsA + byteo) = hreg[l];
            }
            // issue h loads for tile i+1 (covered by compute+pointwise)
            if (ttn < ntiles) {
                const char* hb = (const char*)hsrc + ((long)ttn * 64) * 1024;
#pragma unroll
                for (int l = 0; l < 16; ++l)
                    hreg[l] = *(const uint4*)(hb + (l * 4 + w) * 1024 + lane * 16);
            }
            __syncthreads();   // (b) ldsA populated

            f32x4 acch[3];
#pragma unroll
            for (int g = 0; g < 3; ++g) acch[g] = (f32x4){0.f, 0.f, 0.f, 0.f};

#pragma unroll
            for (int kk = 0; kk < 16; ++kk) {
                int arow = w * 16 + (lane & 15);
                int abyte = (arow * 1024 + kk * 64 + ((lane >> 4) * 16)) ^ ((arow & 7) << 4);
                short8 ah = *(const short8*)((const char*)ldsA + abyte);
#pragma unroll
                for (int g = 0; g < 3; ++g) {
                    int rrow = g * 16 + (lane & 15);
                    int bbyte = (rrow * 1024 + kk * 64 + ((lane >> 4) * 16)) ^ ((rrow & 7) << 4);
                    short8 bfrag = *(const short8*)((const char*)ldsW + bbyte);
                    acch[g] = __builtin_amdgcn_mfma_f32_16x16x32_bf16(ah, bfrag, acch[g], 0, 0, 0);
                }
            }

            // fused GRU pointwise + stores
#pragma unroll
            for (int q = 0; q < 4; ++q) {
                if (rec4[q] >= 0) {
                    int rowl = rbase + q;
                    int r = tt * 64 + rowl;
                    int b = rec4[q] >> 16, st = rec4[q] & 0xffff;
                    int s = st + t;
                    int hby = (rowl * 1024 + j * 2) ^ ((rowl & 7) << 4);
                    float heff = bf2f(*(const unsigned short*)((const char*)ldsA + hby));
                    float rgt = sigm(bf2f(gr[q]) + acch[0][q] + bhr);
                    float zgt = sigm(bf2f(gz[q]) + acch[1][q] + bhz);
                    float ngt = tanh_fast(bf2f(gn[q]) + rgt * (acch[2][q] + bhn));
                    float hnew = (1.f - zgt) * ngt + zgt * heff;
                    unsigned short hb16 = f2bf(hnew);
                    hdst[(long)r * 512 + j] = hb16;
                    rnn[((long)(b * 256 + s)) * 512 + j] = hb16;
                    if (s == 255) hid_out[b * 512 + j] = hnew;
                }
            }
            // issue gi/recs for tile i+1 (covered by next tile's syncs+MFMA)
            if (ttn < ntiles) {
#pragma unroll
                for (int q = 0; q < 4; ++q) {
                    int r = ttn * 64 + rbase + q;
                    if (r < Mt) {
                        rec4[q] = recs[r];
                        const unsigned short* gp = gi + (base + r) * 1536 + j;
                        gr[q] = gp[0]; gz[q] = gp[512]; gn[q] = gp[1024];
                    } else rec4[q] = -1;
                }
            }
        }
        gbar(meta, rgrp, (unsigned int)t);
    }
}

// ---------------------------------------------------------------------------
// Q head (unchanged)
// ---------------------------------------------------------------------------
__global__ __launch_bounds__(256) void qhead(
    const unsigned short* __restrict__ rnn, const float* __restrict__ Wq,
    const float* __restrict__ bq, const int* __restrict__ avail,
    float* __restrict__ qout)
{
    const int w = threadIdx.x >> 6;
    const int lane = threadIdx.x & 63;
    const long row = (long)blockIdx.x * 4 + w;
    const int a = lane & 15;
    const int kc = lane >> 4;
    const unsigned short* hr = rnn + row * H + kc * 128;
    const float* wr = Wq + a * H + kc * 128;
    float sum = 0.f;
#pragma unroll
    for (int i = 0; i < 128; i += 8) {
        short8 hv = *(const short8*)(hr + i);
        float4 wa = *(const float4*)(wr + i);
        float4 wb = *(const float4*)(wr + i + 4);
        sum += bf2f((unsigned short)hv[0]) * wa.x;
        sum += bf2f((unsigned short)hv[1]) * wa.y;
        sum += bf2f((unsigned short)hv[2]) * wa.z;
        sum += bf2f((unsigned short)hv[3]) * wa.w;
        sum += bf2f((unsigned short)hv[4]) * wb.x;
        sum += bf2f((unsigned short)hv[5]) * wb.y;
        sum += bf2f((unsigned short)hv[6]) * wb.z;
        sum += bf2f((unsigned short)hv[7]) * wb.w;
    }
    sum += __shfl_xor(sum, 16);
    sum += __shfl_xor(sum, 32);
    if (kc == 0) {
        float qv = sum + bq[a];
        int av = avail[row * 16 + a];
        if (av == 0) qv -= 1e10f;
        qout[row * 16 + a] = qv;
    }
}

// ---------------------------------------------------------------------------
extern "C" void kernel_launch(void* const* d_in, const int* in_sizes, int n_in,
                              void* d_out, int out_size, void* d_ws, size_t ws_size,
                              hipStream_t stream)
{
    const float* hidden = (const float*)d_in[0];
    const float* x      = (const float*)d_in[1];
    const int*   dones  = (const int*)d_in[2];
    const int*   avail  = (const int*)d_in[3];
    const float* Wl     = (const float*)d_in[4];
    const float* bl     = (const float*)d_in[5];
    const float* ln_g   = (const float*)d_in[6];
    const float* ln_b   = (const float*)d_in[7];
    const float* W_ih   = (const float*)d_in[8];
    const float* W_hh   = (const float*)d_in[9];
    const float* b_ih   = (const float*)d_in[10];
    const float* b_hh   = (const float*)d_in[11];
    const float* Wq     = (const float*)d_in[12];
    const float* bq     = (const float*)d_in[13];

    char* p = (char*)d_ws;
    unsigned short* actA = (unsigned short*)p;                // 16 MB; hst0 after gi GEMM
    unsigned short* hst0 = actA;
    p += (size_t)NROWS * H * 2;
    unsigned short* actB = (unsigned short*)p;                // gi overlays actB+gout (48 MB)
    unsigned short* gi   = actB;
    p += (size_t)NROWS * H * 2;                               // 16 MB
    float* gout = (float*)p; p += (size_t)NROWS * H * 4;      // 32 MB
    unsigned short* rnn  = (unsigned short*)p; p += (size_t)NROWS * H * 2;  // 16 MB
    char* wreg = p;                                           // weights region (hst1 overlay)
    unsigned short* wlb  = (unsigned short*)wreg;             // 2 MB
    unsigned short* wihb = (unsigned short*)(wreg + (size_t)4 * H * H * 2); // 1.5 MB
    unsigned short* hst1 = (unsigned short*)wreg;             // 16 MB (after gi GEMM)
    p += (size_t)NROWS * H * 2;
    int* lenArr = (int*)p;          p += (size_t)NROWS * 4;   // 64 KB
    int* recs   = (int*)p;          p += (size_t)NROWS * 4;   // 64 KB
    int* pmap   = (int*)p;          p += (size_t)NROWS * 4;   // 64 KB
    unsigned int* meta = (unsigned int*)p;  p += 8192;
    unsigned int* hist = meta + 16;
    unsigned int* offs = meta + 288;
    int* Marr = (int*)(meta + 560);
    unsigned int* ssum = meta + 832;

    // 1) convert inputs to bf16; zero meta
    cvt_init<<<9984, 256, 0, stream>>>(x, Wl, W_ih, actA, wlb, wihb, meta);

    // 2) segment machinery
    seg_build<<<64, 256, 0, stream>>>(dones, lenArr, hist);
    seg_offsets<<<1, 256, 0, stream>>>(hist, Marr, offs, ssum);
    seg_scatter<<<64, 256, 0, stream>>>(lenArr, offs, recs);
    pmap_build<<<64, 256, 0, stream>>>(recs, Marr, ssum, lenArr, pmap);

    // 3) MLP stack: 4 x (GEMM f32-out + bias, then LN+ReLU -> bf16)
    unsigned short* cur = actA;
    unsigned short* nxt = actB;
    for (int l = 0; l < 4; ++l) {
        gemm_bt<0><<<512, 256, 0, stream>>>(cur, wlb + (size_t)l * H * H, bl + l * H,
                                            (void*)gout, NROWS, H, H, nullptr);
        ln_relu<<<4096, 256, 0, stream>>>(gout, ln_g + l * H, ln_b + l * H, nxt);
        unsigned short* tsw = cur; cur = nxt; nxt = tsw;
    }
    // cur == actA

    // 4) gi = act @ W_ih^T + b_ih -> bf16, ROW-PERMUTED by pmap (overlays actB+gout)
    gemm_bt<1><<<1536, 256, 0, stream>>>(cur, wihb, b_ih, (void*)gi, NROWS, 3 * H, H, pmap);

    // 5) init h_state rows by rank (overlays actA, free after gi GEMM)
    h_init<<<4096, 256, 0, stream>>>(recs, Marr, dones, hidden, hst0);

    // 6) segment-parallel GRU scan (256 WGs = 32 jg x 8 XCD-rgrp)
    gru_seg_scan<<<256, 256, 0, stream>>>(gi, W_hh, b_hh, Marr, ssum, recs,
                                          hst0, hst1, rnn, (float*)d_out, meta);

    // 7) Q head + availability mask
    qhead<<<4096, 256, 0, stream>>>(rnn, Wq, bq, avail, (float*)d_out + BATCH * H);
}

// Round 5
// 852.859 us; speedup vs baseline: 1.1231x; 1.1231x over previous
//
#include <hip/hip_runtime.h>
#include <hip/hip_bf16.h>

typedef short short8 __attribute__((ext_vector_type(8)));
typedef float f32x4 __attribute__((ext_vector_type(4)));

#define H 512
#define BATCH 64
#define SEQ 256
#define NROWS 16384   // BATCH*SEQ

__device__ __forceinline__ float bf2f(unsigned short u) {
    union { unsigned int i; float f; } v;
    v.i = ((unsigned int)u) << 16;
    return v.f;
}
__device__ __forceinline__ unsigned short f2bf(float f) {
    union { float f; unsigned int i; } v;
    v.f = f;
    unsigned int lsb = (v.i >> 16) & 1u;
    v.i += 0x7fffu + lsb;   // round-to-nearest-even
    return (unsigned short)(v.i >> 16);
}
__device__ __forceinline__ float sigm(float x) { return 1.f / (1.f + __expf(-x)); }
__device__ __forceinline__ float tanh_fast(float x) { return 2.f / (1.f + __expf(-2.f * x)) - 1.f; }

// ---------------------------------------------------------------------------
// convert + init: x->bf16, Wl->bf16, W_ih->bf16; zero FULL meta region (2048 u32)
// ---------------------------------------------------------------------------
__global__ __launch_bounds__(256) void cvt_init(
    const float* __restrict__ x, const float* __restrict__ Wl,
    const float* __restrict__ Wih,
    unsigned short* __restrict__ actA, unsigned short* __restrict__ wlb,
    unsigned short* __restrict__ wihb, unsigned int* __restrict__ meta)
{
    long idx4 = (long)blockIdx.x * 256 + threadIdx.x;
    if (idx4 < 2048) meta[idx4] = 0u;   // covers domain slots + hist + offs + Marr + ssum
    long i = idx4 * 4;
    const long N1 = 8388608;            // x: 16384*512
    const long N2 = N1 + 1048576;       // Wl: 4*512*512
    const long N3 = N2 + 786432;        // W_ih: 1536*512
    const float* src; unsigned short* dst; long off;
    if (i < N1)      { src = x;   dst = actA; off = i; }
    else if (i < N2) { src = Wl;  dst = wlb;  off = i - N1; }
    else if (i < N3) { src = Wih; dst = wihb; off = i - N2; }
    else return;
    float4 v = *(const float4*)(src + off);
    ushort4 o;
    o.x = f2bf(v.x); o.y = f2bf(v.y); o.z = f2bf(v.z); o.w = f2bf(v.w);
    *(ushort4*)(dst + off) = o;
}

// ---------------------------------------------------------------------------
// Segment machinery. Segment = maximal run starting at s where (s==0 || done[b,s]).
// ---------------------------------------------------------------------------
__global__ __launch_bounds__(256) void seg_build(
    const int* __restrict__ dones, int* __restrict__ lenArr,
    unsigned int* __restrict__ hist)
{
    __shared__ int d[256];
    const int b = blockIdx.x, s = threadIdx.x;
    d[s] = dones[b * 256 + s];
    __syncthreads();
    int len = 0;
    bool start = (s == 0) || (d[s] != 0);
    if (start) {
        len = 1;
        while (s + len < 256 && d[s + len] == 0) len++;
        atomicAdd(&hist[len], 1u);
    }
    lenArr[b * 256 + s] = len;
}

// M[t] = #segments with len > t; offs[L]=M[L] (scatter cursors); ssum = prefix(M)
__global__ __launch_bounds__(256) void seg_offsets(
    const unsigned int* __restrict__ hist, int* __restrict__ Marr,
    unsigned int* __restrict__ offs, unsigned int* __restrict__ ssum)
{
    __shared__ unsigned int h[257];
    __shared__ int Msh[257];
    const int t = threadIdx.x;
    h[t] = hist[t];
    if (t == 0) h[256] = hist[256];
    __syncthreads();
    for (int tt = t; tt <= 256; tt += 256) {
        unsigned int m = 0;
        for (int L = tt + 1; L <= 256; ++L) m += h[L];
        Marr[tt] = (int)m;
        offs[tt] = m;
        Msh[tt] = (int)m;
    }
    __syncthreads();
    if (t == 0) {
        unsigned int acc = 0;
        for (int k = 0; k <= 256; ++k) { ssum[k] = acc; acc += (unsigned int)Msh[k]; }
    }
}

// counting-sort scatter: rows sorted by length descending -> alive set is prefix
__global__ __launch_bounds__(256) void seg_scatter(
    const int* __restrict__ lenArr, unsigned int* __restrict__ offs,
    int* __restrict__ recs)
{
    const int b = blockIdx.x, s = threadIdx.x;
    int len = lenArr[b * 256 + s];
    if (len > 0) {
        unsigned int pos = atomicAdd(&offs[len], 1u);
        recs[pos] = (b << 16) | s;
    }
}

// pmap[(b,s)] = ssum[t] + rank : gi GEMM output row permutation
__global__ __launch_bounds__(256) void pmap_build(
    const int* __restrict__ recs, const int* __restrict__ Marr,
    const unsigned int* __restrict__ ssum, const int* __restrict__ lenArr,
    int* __restrict__ pmap)
{
    const int i = blockIdx.x * 256 + threadIdx.x;
    if (i >= Marr[0]) return;
    int rec = recs[i];
    int b = rec >> 16, st = rec & 0xffff;
    int len = lenArr[b * 256 + st];
    for (int t = 0; t < len; ++t) pmap[b * 256 + st + t] = (int)ssum[t] + i;
}

// h_state row init by rank: hidden[b] for the s==0 segment when !done[b,0], else 0.
__global__ __launch_bounds__(256) void h_init(
    const int* __restrict__ recs, const int* __restrict__ Marr,
    const int* __restrict__ dones, const float* __restrict__ hidden,
    unsigned short* __restrict__ hst)
{
    const int w = threadIdx.x >> 6, lane = threadIdx.x & 63;
    const int i = blockIdx.x * 4 + w;
    const int nseg = Marr[0];
    const int c0 = lane * 8;
    unsigned short* dst = hst + (long)i * 512 + c0;
    if (i < nseg) {
        int rec = recs[i];
        int b = rec >> 16, st = rec & 0xffff;
        if (st == 0 && dones[b * 256] == 0) {
            float4 va = *(const float4*)(hidden + b * 512 + c0);
            float4 vb = *(const float4*)(hidden + b * 512 + c0 + 4);
            ushort4 o0 = {f2bf(va.x), f2bf(va.y), f2bf(va.z), f2bf(va.w)};
            ushort4 o1 = {f2bf(vb.x), f2bf(vb.y), f2bf(vb.z), f2bf(vb.w)};
            *(ushort4*)dst = o0; *(ushort4*)(dst + 4) = o1;
            return;
        }
    }
    ushort4 z4 = {0, 0, 0, 0};
    *(ushort4*)dst = z4; *(ushort4*)(dst + 4) = z4;
}

// ---------------------------------------------------------------------------
// GEMM: C[M,N] = A[M,K](bf16) * Bw[N,K]^T(bf16) + bias[N]; optional row remap
// ---------------------------------------------------------------------------
template <int BF16OUT>
__global__ __launch_bounds__(256) void gemm_bt(
    const unsigned short* __restrict__ A, const unsigned short* __restrict__ Bw,
    const float* __restrict__ bias, void* __restrict__ Cout,
    int M, int N, int K, const int* __restrict__ rowmap)
{
    __shared__ unsigned short ldsA[128 * 64];
    __shared__ unsigned short ldsB[128 * 64];
    const int tid = threadIdx.x;
    const int lane = tid & 63;
    const int w = tid >> 6;
    const int nbx = N >> 7;
    const int bm = blockIdx.x / nbx;
    const int bn = blockIdx.x % nbx;
    const long m0 = (long)bm * 128;
    const long n0 = (long)bn * 128;
    const long Kb = (long)K * 2;

    f32x4 acc[4][4];
#pragma unroll
    for (int i = 0; i < 4; ++i)
#pragma unroll
        for (int j = 0; j < 4; ++j) acc[i][j] = (f32x4){0.f, 0.f, 0.f, 0.f};

    for (int kt = 0; kt < K; kt += 64) {
        __syncthreads();
#pragma unroll
        for (int i = 0; i < 4; ++i) {
            int o   = (i * 256 + tid) * 16;
            int row = o >> 7;
            int ch  = (o & 127) >> 4;
            long gcol = (long)kt * 2 + (long)((ch ^ (row & 7)) << 4);
            int ldsoff = (i * 256 + w * 64) * 8;
            __builtin_amdgcn_global_load_lds(
                (const unsigned int*)((const char*)A + (m0 + row) * Kb + gcol),
                (unsigned int*)(ldsA + ldsoff), 16, 0, 0);
            __builtin_amdgcn_global_load_lds(
                (const unsigned int*)((const char*)Bw + (n0 + row) * Kb + gcol),
                (unsigned int*)(ldsB + ldsoff), 16, 0, 0);
        }
        __syncthreads();

#pragma unroll
        for (int k2 = 0; k2 < 2; ++k2) {
            short8 af[4], bfr[4];
#pragma unroll
            for (int i = 0; i < 4; ++i) {
                int row = (w >> 1) * 64 + i * 16 + (lane & 15);
                int byteo = (row * 128 + k2 * 64 + ((lane >> 4) * 16)) ^ ((row & 7) << 4);
                af[i] = *(const short8*)((const char*)ldsA + byteo);
            }
#pragma unroll
            for (int j = 0; j < 4; ++j) {
                int row = (w & 1) * 64 + j * 16 + (lane & 15);
                int byteo = (row * 128 + k2 * 64 + ((lane >> 4) * 16)) ^ ((row & 7) << 4);
                bfr[j] = *(const short8*)((const char*)ldsB + byteo);
            }
#pragma unroll
            for (int i = 0; i < 4; ++i)
#pragma unroll
                for (int j = 0; j < 4; ++j)
                    acc[i][j] = __builtin_amdgcn_mfma_f32_16x16x32_bf16(af[i], bfr[j], acc[i][j], 0, 0, 0);
        }
    }

#pragma unroll
    for (int j = 0; j < 4; ++j) {
        long n = n0 + (w & 1) * 64 + j * 16 + (lane & 15);
        float bz = bias ? bias[n] : 0.f;
#pragma unroll
        for (int i = 0; i < 4; ++i) {
#pragma unroll
            for (int r = 0; r < 4; ++r) {
                long m = m0 + (w >> 1) * 64 + i * 16 + (lane >> 4) * 4 + r;
                long mm = rowmap ? (long)rowmap[m] : m;
                float v = acc[i][j][r] + bz;
                if (BF16OUT) ((unsigned short*)Cout)[mm * N + n] = f2bf(v);
                else         ((float*)Cout)[mm * N + n] = v;
            }
        }
    }
}

// ---------------------------------------------------------------------------
// LayerNorm + ReLU (unchanged)
// ---------------------------------------------------------------------------
__global__ __launch_bounds__(256) void ln_relu(
    const float* __restrict__ X, const float* __restrict__ g,
    const float* __restrict__ b, unsigned short* __restrict__ Y)
{
    const int w = threadIdx.x >> 6;
    const int lane = threadIdx.x & 63;
    const long row = (long)blockIdx.x * 4 + w;
    const float* xr = X + row * H;
    float4 v0 = *(const float4*)(xr + lane * 4);
    float4 v1 = *(const float4*)(xr + 256 + lane * 4);
    float s = v0.x + v0.y + v0.z + v0.w + v1.x + v1.y + v1.z + v1.w;
    float q = v0.x * v0.x + v0.y * v0.y + v0.z * v0.z + v0.w * v0.w
            + v1.x * v1.x + v1.y * v1.y + v1.z * v1.z + v1.w * v1.w;
#pragma unroll
    for (int off = 1; off < 64; off <<= 1) {
        s += __shfl_xor(s, off);
        q += __shfl_xor(q, off);
    }
    float mu = s * (1.f / 512.f);
    float var = q * (1.f / 512.f) - mu * mu;
    float rs = rsqrtf(var + 1e-5f);
    int c0 = lane * 4;
    float4 ga = *(const float4*)(g + c0);
    float4 ba = *(const float4*)(b + c0);
    float4 gb = *(const float4*)(g + 256 + c0);
    float4 bb = *(const float4*)(b + 256 + c0);
    ushort4 o0, o1;
    o0.x = f2bf(fmaxf(0.f, (v0.x - mu) * rs * ga.x + ba.x));
    o0.y = f2bf(fmaxf(0.f, (v0.y - mu) * rs * ga.y + ba.y));
    o0.z = f2bf(fmaxf(0.f, (v0.z - mu) * rs * ga.z + ba.z));
    o0.w = f2bf(fmaxf(0.f, (v0.w - mu) * rs * ga.w + ba.w));
    o1.x = f2bf(fmaxf(0.f, (v1.x - mu) * rs * gb.x + bb.x));
    o1.y = f2bf(fmaxf(0.f, (v1.y - mu) * rs * gb.y + bb.y));
    o1.z = f2bf(fmaxf(0.f, (v1.z - mu) * rs * gb.z + bb.z));
    o1.w = f2bf(fmaxf(0.f, (v1.w - mu) * rs * gb.w + bb.w));
    *(ushort4*)(Y + row * H + c0) = o0;
    *(ushort4*)(Y + row * H + 256 + c0) = o1;
}

// ---------------------------------------------------------------------------
// Domain-local barrier: 32 WGs of one domain. dm[0]=counter, dm[16]=release.
// Epoch-monotone (same proven scheme as r1-r3, scoped to 32 WGs).
// ---------------------------------------------------------------------------
__device__ __forceinline__ void dbar(unsigned int* __restrict__ dm,
                                     unsigned int epoch)
{
    __syncthreads();
    if (threadIdx.x == 0) {
        unsigned int p = __hip_atomic_fetch_add(&dm[0], 1u, __ATOMIC_ACQ_REL,
                                                __HIP_MEMORY_SCOPE_AGENT);
        if (p == (epoch + 1u) * 32u - 1u) {
            __hip_atomic_store(&dm[16], epoch + 1u, __ATOMIC_RELEASE,
                               __HIP_MEMORY_SCOPE_AGENT);
        } else {
            while (__hip_atomic_load(&dm[16], __ATOMIC_ACQUIRE,
                                     __HIP_MEMORY_SCOPE_AGENT) <= epoch)
                __builtin_amdgcn_s_sleep(2);
        }
    }
    __syncthreads();
}

// ---------------------------------------------------------------------------
// Segment-parallel GRU scan, 8 INDEPENDENT domains (XCD-colocated), LDS-free
// A-path. Grid 256 = 32 jg (16 cols, 48-row W_hh slice in LDS) x 8 dom.
// Tile tt owned by dom = tt%8 forever; tile(t+1) depends only on same-domain
// tiles(t) -> only a 32-WG domain barrier per step. A-fragments, gi, heff are
// loaded straight into VGPRs (waves never share A rows -> no LDS staging).
// ---------------------------------------------------------------------------
__global__ __launch_bounds__(256, 1) void gru_seg_scan(
    const unsigned short* __restrict__ gi,   // [16384,1536] bf16, rank-permuted
    const float* __restrict__ Whh,           // [1536,512] f32
    const float* __restrict__ bhh,           // [1536] f32
    const int* __restrict__ Marr,
    const unsigned int* __restrict__ ssum,
    const int* __restrict__ recs,
    unsigned short* __restrict__ hstA,       // by rank, read when t even
    unsigned short* __restrict__ hstB,
    unsigned short* __restrict__ rnn,        // [B*S,512] bf16
    float* __restrict__ hid_out,             // [64,512] f32
    unsigned int* __restrict__ meta)
{
    __shared__ unsigned short ldsW[48 * 512];   // 48 KB (W slice only)
    const int tid = threadIdx.x;
    const int lane = tid & 63;
    const int w = tid >> 6;
    const int jg = blockIdx.x >> 3;
    const int dom = blockIdx.x & 7;             // XCD domain (round-robin %8)
    const int j0 = jg * 16;

    // stage W_hh slice (rows: r gate j0..+15, z, n), f32 -> bf16, XOR swizzle
    for (int e = tid; e < 48 * 512; e += 256) {
        int rrow = e >> 9;
        int col = e & 511;
        int gate = rrow >> 4;
        int jl = rrow & 15;
        float v = Whh[((long)(gate * 512 + j0 + jl)) * 512 + col];
        int byteo = (rrow * 1024 + col * 2) ^ ((rrow & 7) << 4);
        *(unsigned short*)((char*)ldsW + byteo) = f2bf(v);
    }

    const int j = j0 + (lane & 15);
    const float bhr = bhh[j];
    const float bhz = bhh[512 + j];
    const float bhn = bhh[1024 + j];
    const int rbase = w * 16 + (lane >> 4) * 4;     // pointwise rows (local)
    const int arowl = w * 16 + (lane & 15);         // A-frag row (local)
    const int kcol0 = (lane >> 4) * 8;              // A-frag k base
    unsigned int* dmeta = meta + 64 * dom;
    __syncthreads();   // ldsW ready

    for (int t = 0; t < 256; ++t) {
        const int Mt = Marr[t];
        if (Mt == 0) break;
        const int ntiles = (Mt + 63) >> 6;
        if (dom >= ntiles) break;   // this domain owns nothing from here on
        const long base = (long)ssum[t];
        const unsigned short* hsrc = (t & 1) ? hstB : hstA;
        unsigned short* hdst = (t & 1) ? hstA : hstB;

        for (int tt = dom; tt < ntiles; tt += 8) {
            const int r0 = tt * 64;

            // A-fragments straight from global (row r0+arowl, k = kcol0+kk*32)
            const unsigned short* arowp = hsrc + ((long)(r0 + arowl)) * 512 + kcol0;
            short8 af[16];
#pragma unroll
            for (int kk = 0; kk < 16; ++kk)
                af[kk] = *(const short8*)(arowp + kk * 32);

            // gi + recs + heff for the 4 pointwise rows
            int rec4[4];
            unsigned short gr[4], gz[4], gn[4], he[4];
#pragma unroll
            for (int q = 0; q < 4; ++q) {
                int r = r0 + rbase + q;
                if (r < Mt) {
                    rec4[q] = recs[r];
                    const unsigned short* gp = gi + (base + r) * 1536 + j;
                    gr[q] = gp[0]; gz[q] = gp[512]; gn[q] = gp[1024];
                    he[q] = hsrc[(long)r * 512 + j];
                } else rec4[q] = -1;
            }

            f32x4 acch[3];
#pragma unroll
            for (int g = 0; g < 3; ++g) acch[g] = (f32x4){0.f, 0.f, 0.f, 0.f};

#pragma unroll
            for (int kk = 0; kk < 16; ++kk) {
#pragma unroll
                for (int g = 0; g < 3; ++g) {
                    int rrow = g * 16 + (lane & 15);
                    int bbyte = (rrow * 1024 + kk * 64 + ((lane >> 4) * 16)) ^ ((rrow & 7) << 4);
                    short8 bfrag = *(const short8*)((const char*)ldsW + bbyte);
                    acch[g] = __builtin_amdgcn_mfma_f32_16x16x32_bf16(af[kk], bfrag, acch[g], 0, 0, 0);
                }
            }

            // fused GRU pointwise + stores
#pragma unroll
            for (int q = 0; q < 4; ++q) {
                if (rec4[q] >= 0) {
                    int r = r0 + rbase + q;
                    int b = rec4[q] >> 16, st = rec4[q] & 0xffff;
                    int s = st + t;
                    float heff = bf2f(he[q]);
                    float rgt = sigm(bf2f(gr[q]) + acch[0][q] + bhr);
                    float zgt = sigm(bf2f(gz[q]) + acch[1][q] + bhz);
                    float ngt = tanh_fast(bf2f(gn[q]) + rgt * (acch[2][q] + bhn));
                    float hnew = (1.f - zgt) * ngt + zgt * heff;
                    unsigned short hb16 = f2bf(hnew);
                    hdst[(long)r * 512 + j] = hb16;
                    rnn[((long)(b * 256 + s)) * 512 + j] = hb16;
                    if (s == 255) hid_out[b * 512 + j] = hnew;
                }
            }
        }
        dbar(dmeta, (unsigned int)t);
    }
}

// ---------------------------------------------------------------------------
// Q head (unchanged)
// ---------------------------------------------------------------------------
__global__ __launch_bounds__(256) void qhead(
    const unsigned short* __restrict__ rnn, const float* __restrict__ Wq,
    const float* __restrict__ bq, const int* __restrict__ avail,
    float* __restrict__ qout)
{
    const int w = threadIdx.x >> 6;
    const int lane = threadIdx.x & 63;
    const long row = (long)blockIdx.x * 4 + w;
    const int a = lane & 15;
    const int kc = lane >> 4;
    const unsigned short* hr = rnn + row * H + kc * 128;
    const float* wr = Wq + a * H + kc * 128;
    float sum = 0.f;
#pragma unroll
    for (int i = 0; i < 128; i += 8) {
        short8 hv = *(const short8*)(hr + i);
        float4 wa = *(const float4*)(wr + i);
        float4 wb = *(const float4*)(wr + i + 4);
        sum += bf2f((unsigned short)hv[0]) * wa.x;
        sum += bf2f((unsigned short)hv[1]) * wa.y;
        sum += bf2f((unsigned short)hv[2]) * wa.z;
        sum += bf2f((unsigned short)hv[3]) * wa.w;
        sum += bf2f((unsigned short)hv[4]) * wb.x;
        sum += bf2f((unsigned short)hv[5]) * wb.y;
        sum += bf2f((unsigned short)hv[6]) * wb.z;
        sum += bf2f((unsigned short)hv[7]) * wb.w;
    }
    sum += __shfl_xor(sum, 16);
    sum += __shfl_xor(sum, 32);
    if (kc == 0) {
        float qv = sum + bq[a];
        int av = avail[row * 16 + a];
        if (av == 0) qv -= 1e10f;
        qout[row * 16 + a] = qv;
    }
}

// ---------------------------------------------------------------------------
extern "C" void kernel_launch(void* const* d_in, const int* in_sizes, int n_in,
                              void* d_out, int out_size, void* d_ws, size_t ws_size,
                              hipStream_t stream)
{
    const float* hidden = (const float*)d_in[0];
    const float* x      = (const float*)d_in[1];
    const int*   dones  = (const int*)d_in[2];
    const int*   avail  = (const int*)d_in[3];
    const float* Wl     = (const float*)d_in[4];
    const float* bl     = (const float*)d_in[5];
    const float* ln_g   = (const float*)d_in[6];
    const float* ln_b   = (const float*)d_in[7];
    const float* W_ih   = (const float*)d_in[8];
    const float* W_hh   = (const float*)d_in[9];
    const float* b_ih   = (const float*)d_in[10];
    const float* b_hh   = (const float*)d_in[11];
    const float* Wq     = (const float*)d_in[12];
    const float* bq     = (const float*)d_in[13];

    char* p = (char*)d_ws;
    unsigned short* actA = (unsigned short*)p;                // 16 MB; hst0 after gi GEMM
    unsigned short* hst0 = actA;
    p += (size_t)NROWS * H * 2;
    unsigned short* actB = (unsigned short*)p;                // gi overlays actB+gout (48 MB)
    unsigned short* gi   = actB;
    p += (size_t)NROWS * H * 2;                               // 16 MB
    float* gout = (float*)p; p += (size_t)NROWS * H * 4;      // 32 MB
    unsigned short* rnn  = (unsigned short*)p; p += (size_t)NROWS * H * 2;  // 16 MB
    char* wreg = p;                                           // weights region (hst1 overlay)
    unsigned short* wlb  = (unsigned short*)wreg;             // 2 MB
    unsigned short* wihb = (unsigned short*)(wreg + (size_t)4 * H * H * 2); // 1.5 MB
    unsigned short* hst1 = (unsigned short*)wreg;             // 16 MB (after gi GEMM)
    p += (size_t)NROWS * H * 2;
    int* lenArr = (int*)p;          p += (size_t)NROWS * 4;   // 64 KB
    int* recs   = (int*)p;          p += (size_t)NROWS * 4;   // 64 KB
    int* pmap   = (int*)p;          p += (size_t)NROWS * 4;   // 64 KB
    unsigned int* meta = (unsigned int*)p;  p += 8192;        // 2048 u32, ALL zeroed
    unsigned int* hist = meta + 512;    // 257 u32  (domains use meta[0..511])
    unsigned int* offs = meta + 784;    // 257 u32
    int* Marr = (int*)(meta + 1056);    // 257 i32
    unsigned int* ssum = meta + 1328;   // 257 u32 (ends at 1585 < 2048)

    // 1) convert inputs to bf16; zero meta (incl. 8 domain barrier slots)
    cvt_init<<<9984, 256, 0, stream>>>(x, Wl, W_ih, actA, wlb, wihb, meta);

    // 2) segment machinery
    seg_build<<<64, 256, 0, stream>>>(dones, lenArr, hist);
    seg_offsets<<<1, 256, 0, stream>>>(hist, Marr, offs, ssum);
    seg_scatter<<<64, 256, 0, stream>>>(lenArr, offs, recs);
    pmap_build<<<64, 256, 0, stream>>>(recs, Marr, ssum, lenArr, pmap);

    // 3) MLP stack: 4 x (GEMM f32-out + bias, then LN+ReLU -> bf16)
    unsigned short* cur = actA;
    unsigned short* nxt = actB;
    for (int l = 0; l < 4; ++l) {
        gemm_bt<0><<<512, 256, 0, stream>>>(cur, wlb + (size_t)l * H * H, bl + l * H,
                                            (void*)gout, NROWS, H, H, nullptr);
        ln_relu<<<4096, 256, 0, stream>>>(gout, ln_g + l * H, ln_b + l * H, nxt);
        unsigned short* tsw = cur; cur = nxt; nxt = tsw;
    }
    // cur == actA

    // 4) gi = act @ W_ih^T + b_ih -> bf16, ROW-PERMUTED by pmap (overlays actB+gout)
    gemm_bt<1><<<1536, 256, 0, stream>>>(cur, wihb, b_ih, (void*)gi, NROWS, 3 * H, H, pmap);

    // 5) init h_state rows by rank (overlays actA, free after gi GEMM)
    h_init<<<4096, 256, 0, stream>>>(recs, Marr, dones, hidden, hst0);

    // 6) segment-parallel GRU scan (8 independent 32-WG domains)
    gru_seg_scan<<<256, 256, 0, stream>>>(gi, W_hh, b_hh, Marr, ssum, recs,
                                          hst0, hst1, rnn, (float*)d_out, meta);

    // 7) Q head + availability mask
    qhead<<<4096, 256, 0, stream>>>(rnn, Wq, bq, avail, (float*)d_out + BATCH * H);
}

// Round 6
// 811.392 us; speedup vs baseline: 1.1805x; 1.0511x over previous
//
#include <hip/hip_runtime.h>
#include <hip/hip_bf16.h>

typedef short short8 __attribute__((ext_vector_type(8)));
typedef float f32x4 __attribute__((ext_vector_type(4)));

#define H 512
#define BATCH 64
#define SEQ 256
#define NROWS 16384   // BATCH*SEQ

__device__ __forceinline__ float bf2f(unsigned short u) {
    union { unsigned int i; float f; } v;
    v.i = ((unsigned int)u) << 16;
    return v.f;
}
__device__ __forceinline__ unsigned short f2bf(float f) {
    union { float f; unsigned int i; } v;
    v.f = f;
    unsigned int lsb = (v.i >> 16) & 1u;
    v.i += 0x7fffu + lsb;   // round-to-nearest-even
    return (unsigned short)(v.i >> 16);
}
__device__ __forceinline__ float sigm(float x) { return 1.f / (1.f + __expf(-x)); }
__device__ __forceinline__ float tanh_fast(float x) { return 2.f / (1.f + __expf(-2.f * x)) - 1.f; }

// ---------------------------------------------------------------------------
// convert + init: x->bf16, Wl->bf16, W_ih->bf16; zero FULL meta region (2048 u32)
// ---------------------------------------------------------------------------
__global__ __launch_bounds__(256) void cvt_init(
    const float* __restrict__ x, const float* __restrict__ Wl,
    const float* __restrict__ Wih,
    unsigned short* __restrict__ actA, unsigned short* __restrict__ wlb,
    unsigned short* __restrict__ wihb, unsigned int* __restrict__ meta)
{
    long idx4 = (long)blockIdx.x * 256 + threadIdx.x;
    if (idx4 < 2048) meta[idx4] = 0u;
    long i = idx4 * 4;
    const long N1 = 8388608;            // x: 16384*512
    const long N2 = N1 + 1048576;       // Wl: 4*512*512
    const long N3 = N2 + 786432;        // W_ih: 1536*512
    const float* src; unsigned short* dst; long off;
    if (i < N1)      { src = x;   dst = actA; off = i; }
    else if (i < N2) { src = Wl;  dst = wlb;  off = i - N1; }
    else if (i < N3) { src = Wih; dst = wihb; off = i - N2; }
    else return;
    float4 v = *(const float4*)(src + off);
    ushort4 o;
    o.x = f2bf(v.x); o.y = f2bf(v.y); o.z = f2bf(v.z); o.w = f2bf(v.w);
    *(ushort4*)(dst + off) = o;
}

// ---------------------------------------------------------------------------
// Segment machinery. Segment = maximal run starting at s where (s==0 || done[b,s]).
// ---------------------------------------------------------------------------
__global__ __launch_bounds__(256) void seg_build(
    const int* __restrict__ dones, int* __restrict__ lenArr,
    unsigned int* __restrict__ hist)
{
    __shared__ int d[256];
    const int b = blockIdx.x, s = threadIdx.x;
    d[s] = dones[b * 256 + s];
    __syncthreads();
    int len = 0;
    bool start = (s == 0) || (d[s] != 0);
    if (start) {
        len = 1;
        while (s + len < 256 && d[s + len] == 0) len++;
        atomicAdd(&hist[len], 1u);
    }
    lenArr[b * 256 + s] = len;
}

__global__ __launch_bounds__(256) void seg_offsets(
    const unsigned int* __restrict__ hist, int* __restrict__ Marr,
    unsigned int* __restrict__ offs, unsigned int* __restrict__ ssum)
{
    __shared__ unsigned int h[257];
    __shared__ int Msh[257];
    const int t = threadIdx.x;
    h[t] = hist[t];
    if (t == 0) h[256] = hist[256];
    __syncthreads();
    for (int tt = t; tt <= 256; tt += 256) {
        unsigned int m = 0;
        for (int L = tt + 1; L <= 256; ++L) m += h[L];
        Marr[tt] = (int)m;
        offs[tt] = m;
        Msh[tt] = (int)m;
    }
    __syncthreads();
    if (t == 0) {
        unsigned int acc = 0;
        for (int k = 0; k <= 256; ++k) { ssum[k] = acc; acc += (unsigned int)Msh[k]; }
    }
}

__global__ __launch_bounds__(256) void seg_scatter(
    const int* __restrict__ lenArr, unsigned int* __restrict__ offs,
    int* __restrict__ recs)
{
    const int b = blockIdx.x, s = threadIdx.x;
    int len = lenArr[b * 256 + s];
    if (len > 0) {
        unsigned int pos = atomicAdd(&offs[len], 1u);
        recs[pos] = (b << 16) | s;
    }
}

__global__ __launch_bounds__(256) void pmap_build(
    const int* __restrict__ recs, const int* __restrict__ Marr,
    const unsigned int* __restrict__ ssum, const int* __restrict__ lenArr,
    int* __restrict__ pmap)
{
    const int i = blockIdx.x * 256 + threadIdx.x;
    if (i >= Marr[0]) return;
    int rec = recs[i];
    int b = rec >> 16, st = rec & 0xffff;
    int len = lenArr[b * 256 + st];
    for (int t = 0; t < len; ++t) pmap[b * 256 + st + t] = (int)ssum[t] + i;
}

__global__ __launch_bounds__(256) void h_init(
    const int* __restrict__ recs, const int* __restrict__ Marr,
    const int* __restrict__ dones, const float* __restrict__ hidden,
    unsigned short* __restrict__ hst)
{
    const int w = threadIdx.x >> 6, lane = threadIdx.x & 63;
    const int i = blockIdx.x * 4 + w;
    const int nseg = Marr[0];
    const int c0 = lane * 8;
    unsigned short* dst = hst + (long)i * 512 + c0;
    if (i < nseg) {
        int rec = recs[i];
        int b = rec >> 16, st = rec & 0xffff;
        if (st == 0 && dones[b * 256] == 0) {
            float4 va = *(const float4*)(hidden + b * 512 + c0);
            float4 vb = *(const float4*)(hidden + b * 512 + c0 + 4);
            ushort4 o0 = {f2bf(va.x), f2bf(va.y), f2bf(va.z), f2bf(va.w)};
            ushort4 o1 = {f2bf(vb.x), f2bf(vb.y), f2bf(vb.z), f2bf(vb.w)};
            *(ushort4*)dst = o0; *(ushort4*)(dst + 4) = o1;
            return;
        }
    }
    ushort4 z4 = {0, 0, 0, 0};
    *(ushort4*)dst = z4; *(ushort4*)(dst + 4) = z4;
}

// ---------------------------------------------------------------------------
// Fused MLP layer: out = relu(LN(A @ W^T + bias)) in bf16.
// Tile: 64 rows x 512 cols per WG (full row -> LN is WG-local).
// Wave w owns cols [w*128, w*128+128). acc[4][8] f32x4 per lane.
// ---------------------------------------------------------------------------
__global__ __launch_bounds__(256) void gemm_ln(
    const unsigned short* __restrict__ A,   // [16384,512] bf16
    const unsigned short* __restrict__ W,   // [512,512] bf16 (row n = out col)
    const float* __restrict__ bias, const float* __restrict__ g,
    const float* __restrict__ b, unsigned short* __restrict__ Out)
{
    __shared__ unsigned short ldsA[64 * 64];    // 8 KB
    __shared__ unsigned short ldsW[512 * 64];   // 64 KB
    __shared__ float red[64 * 8];               // 2 KB: [row][wave*2 + {s,q}]
    const int tid = threadIdx.x;
    const int lane = tid & 63;
    const int w = tid >> 6;
    const long m0 = (long)blockIdx.x * 64;

    f32x4 acc[4][8];
#pragma unroll
    for (int i = 0; i < 4; ++i)
#pragma unroll
        for (int jn = 0; jn < 8; ++jn) acc[i][jn] = (f32x4){0.f, 0.f, 0.f, 0.f};

    for (int kt = 0; kt < 512; kt += 64) {
        __syncthreads();
        // stage A tile: 64 rows x 128B (2 rounds)
#pragma unroll
        for (int i = 0; i < 2; ++i) {
            int o = (i * 256 + tid) * 16;
            int row = o >> 7;
            int ch = (o & 127) >> 4;
            long gcol = (long)kt * 2 + (long)((ch ^ (row & 7)) << 4);
            __builtin_amdgcn_global_load_lds(
                (const unsigned int*)((const char*)A + (m0 + row) * 1024 + gcol),
                (unsigned int*)(ldsA + (i * 256 + w * 64) * 8), 16, 0, 0);
        }
        // stage W tile: 512 rows x 128B (16 rounds)
#pragma unroll
        for (int i = 0; i < 16; ++i) {
            int o = (i * 256 + tid) * 16;
            int row = o >> 7;
            int ch = (o & 127) >> 4;
            long gcol = (long)kt * 2 + (long)((ch ^ (row & 7)) << 4);
            __builtin_amdgcn_global_load_lds(
                (const unsigned int*)((const char*)W + (long)row * 1024 + gcol),
                (unsigned int*)(ldsW + (i * 256 + w * 64) * 8), 16, 0, 0);
        }
        __syncthreads();

#pragma unroll
        for (int k2 = 0; k2 < 2; ++k2) {
            short8 af[4], bfr[8];
#pragma unroll
            for (int i = 0; i < 4; ++i) {
                int row = i * 16 + (lane & 15);
                int byteo = (row * 128 + k2 * 64 + ((lane >> 4) * 16)) ^ ((row & 7) << 4);
                af[i] = *(const short8*)((const char*)ldsA + byteo);
            }
#pragma unroll
            for (int jn = 0; jn < 8; ++jn) {
                int row = w * 128 + jn * 16 + (lane & 15);
                int byteo = (row * 128 + k2 * 64 + ((lane >> 4) * 16)) ^ ((row & 7) << 4);
                bfr[jn] = *(const short8*)((const char*)ldsW + byteo);
            }
#pragma unroll
            for (int i = 0; i < 4; ++i)
#pragma unroll
                for (int jn = 0; jn < 8; ++jn)
                    acc[i][jn] = __builtin_amdgcn_mfma_f32_16x16x32_bf16(af[i], bfr[jn], acc[i][jn], 0, 0, 0);
        }
    }

    // bias add, then LN row sums
    float bz[8], gl[8], bl2[8];
#pragma unroll
    for (int jn = 0; jn < 8; ++jn) {
        int n = w * 128 + jn * 16 + (lane & 15);
        bz[jn] = bias[n]; gl[jn] = g[n]; bl2[jn] = b[n];
    }
#pragma unroll
    for (int i = 0; i < 4; ++i)
#pragma unroll
        for (int jn = 0; jn < 8; ++jn)
#pragma unroll
            for (int r = 0; r < 4; ++r) acc[i][jn][r] += bz[jn];

    // per-(mf,r) partial sums over this wave's 128 cols, reduced across 16 lanes
#pragma unroll
    for (int i = 0; i < 4; ++i) {
#pragma unroll
        for (int r = 0; r < 4; ++r) {
            float sv = 0.f, qv = 0.f;
#pragma unroll
            for (int jn = 0; jn < 8; ++jn) {
                float v = acc[i][jn][r];
                sv += v; qv += v * v;
            }
            sv += __shfl_xor(sv, 1); qv += __shfl_xor(qv, 1);
            sv += __shfl_xor(sv, 2); qv += __shfl_xor(qv, 2);
            sv += __shfl_xor(sv, 4); qv += __shfl_xor(qv, 4);
            sv += __shfl_xor(sv, 8); qv += __shfl_xor(qv, 8);
            if ((lane & 15) == 0) {
                int row = i * 16 + (lane >> 4) * 4 + r;
                red[row * 8 + w * 2] = sv;
                red[row * 8 + w * 2 + 1] = qv;
            }
        }
    }
    __syncthreads();

#pragma unroll
    for (int i = 0; i < 4; ++i) {
#pragma unroll
        for (int r = 0; r < 4; ++r) {
            int row = i * 16 + (lane >> 4) * 4 + r;
            float s_tot = red[row * 8 + 0] + red[row * 8 + 2] + red[row * 8 + 4] + red[row * 8 + 6];
            float q_tot = red[row * 8 + 1] + red[row * 8 + 3] + red[row * 8 + 5] + red[row * 8 + 7];
            float mu = s_tot * (1.f / 512.f);
            float var = q_tot * (1.f / 512.f) - mu * mu;
            float rs = rsqrtf(var + 1e-5f);
#pragma unroll
            for (int jn = 0; jn < 8; ++jn) {
                int n = w * 128 + jn * 16 + (lane & 15);
                float v = fmaxf(0.f, (acc[i][jn][r] - mu) * rs * gl[jn] + bl2[jn]);
                Out[(m0 + row) * 512 + n] = f2bf(v);
            }
        }
    }
}

// ---------------------------------------------------------------------------
// GEMM (for gi): C = A * Bw^T + bias, row-permuted bf16 out. (r5 unchanged)
// ---------------------------------------------------------------------------
__global__ __launch_bounds__(256) void gemm_bt(
    const unsigned short* __restrict__ A, const unsigned short* __restrict__ Bw,
    const float* __restrict__ bias, unsigned short* __restrict__ Cout,
    int M, int N, int K, const int* __restrict__ rowmap)
{
    __shared__ unsigned short ldsA[128 * 64];
    __shared__ unsigned short ldsB[128 * 64];
    const int tid = threadIdx.x;
    const int lane = tid & 63;
    const int w = tid >> 6;
    const int nbx = N >> 7;
    const int bm = blockIdx.x / nbx;
    const int bn = blockIdx.x % nbx;
    const long m0 = (long)bm * 128;
    const long n0 = (long)bn * 128;
    const long Kb = (long)K * 2;

    f32x4 acc[4][4];
#pragma unroll
    for (int i = 0; i < 4; ++i)
#pragma unroll
        for (int j = 0; j < 4; ++j) acc[i][j] = (f32x4){0.f, 0.f, 0.f, 0.f};

    for (int kt = 0; kt < K; kt += 64) {
        __syncthreads();
#pragma unroll
        for (int i = 0; i < 4; ++i) {
            int o   = (i * 256 + tid) * 16;
            int row = o >> 7;
            int ch  = (o & 127) >> 4;
            long gcol = (long)kt * 2 + (long)((ch ^ (row & 7)) << 4);
            int ldsoff = (i * 256 + w * 64) * 8;
            __builtin_amdgcn_global_load_lds(
                (const unsigned int*)((const char*)A + (m0 + row) * Kb + gcol),
                (unsigned int*)(ldsA + ldsoff), 16, 0, 0);
            __builtin_amdgcn_global_load_lds(
                (const unsigned int*)((const char*)Bw + (n0 + row) * Kb + gcol),
                (unsigned int*)(ldsB + ldsoff), 16, 0, 0);
        }
        __syncthreads();

#pragma unroll
        for (int k2 = 0; k2 < 2; ++k2) {
            short8 af[4], bfr[4];
#pragma unroll
            for (int i = 0; i < 4; ++i) {
                int row = (w >> 1) * 64 + i * 16 + (lane & 15);
                int byteo = (row * 128 + k2 * 64 + ((lane >> 4) * 16)) ^ ((row & 7) << 4);
                af[i] = *(const short8*)((const char*)ldsA + byteo);
            }
#pragma unroll
            for (int j = 0; j < 4; ++j) {
                int row = (w & 1) * 64 + j * 16 + (lane & 15);
                int byteo = (row * 128 + k2 * 64 + ((lane >> 4) * 16)) ^ ((row & 7) << 4);
                bfr[j] = *(const short8*)((const char*)ldsB + byteo);
            }
#pragma unroll
            for (int i = 0; i < 4; ++i)
#pragma unroll
                for (int j = 0; j < 4; ++j)
                    acc[i][j] = __builtin_amdgcn_mfma_f32_16x16x32_bf16(af[i], bfr[j], acc[i][j], 0, 0, 0);
        }
    }

#pragma unroll
    for (int j = 0; j < 4; ++j) {
        long n = n0 + (w & 1) * 64 + j * 16 + (lane & 15);
        float bz = bias ? bias[n] : 0.f;
#pragma unroll
        for (int i = 0; i < 4; ++i) {
#pragma unroll
            for (int r = 0; r < 4; ++r) {
                long m = m0 + (w >> 1) * 64 + i * 16 + (lane >> 4) * 4 + r;
                long mm = rowmap ? (long)rowmap[m] : m;
                Cout[mm * N + n] = f2bf(acc[i][j][r] + bz);
            }
        }
    }
}

// ---------------------------------------------------------------------------
// Domain-local barrier: 32 WGs of one domain. dm[0]=counter, dm[16]=release.
// ---------------------------------------------------------------------------
__device__ __forceinline__ void dbar(unsigned int* __restrict__ dm,
                                     unsigned int epoch)
{
    __syncthreads();
    if (threadIdx.x == 0) {
        unsigned int p = __hip_atomic_fetch_add(&dm[0], 1u, __ATOMIC_ACQ_REL,
                                                __HIP_MEMORY_SCOPE_AGENT);
        if (p == (epoch + 1u) * 32u - 1u) {
            __hip_atomic_store(&dm[16], epoch + 1u, __ATOMIC_RELEASE,
                               __HIP_MEMORY_SCOPE_AGENT);
        } else {
            while (__hip_atomic_load(&dm[16], __ATOMIC_ACQUIRE,
                                     __HIP_MEMORY_SCOPE_AGENT) <= epoch)
                __builtin_amdgcn_s_sleep(2);
        }
    }
    __syncthreads();
}

// ---------------------------------------------------------------------------
// Segment-parallel GRU scan, 8 independent domains; cross-barrier gi prefetch.
// Grid 256 = 32 jg x 8 dom. Tile tt owned by dom = tt%8 forever.
// gi/recs addresses are h-independent -> prefetched BEFORE the barrier so
// their HBM latency overlaps the barrier wait. Marr/ssum live in LDS.
// Post-barrier critical path: A-rows + heff (own-XCD L2) + MFMA + pointwise.
// ---------------------------------------------------------------------------
__global__ __launch_bounds__(256, 1) void gru_seg_scan(
    const unsigned short* __restrict__ gi,   // [16384,1536] bf16, rank-permuted
    const float* __restrict__ Whh,           // [1536,512] f32
    const float* __restrict__ bhh,           // [1536] f32
    const int* __restrict__ Marr,
    const unsigned int* __restrict__ ssum,
    const int* __restrict__ recs,
    unsigned short* __restrict__ hstA,       // by rank, read when t even
    unsigned short* __restrict__ hstB,
    unsigned short* __restrict__ rnn,        // [B*S,512] bf16
    float* __restrict__ hid_out,             // [64,512] f32
    unsigned int* __restrict__ meta)
{
    __shared__ unsigned short ldsW[48 * 512];   // 48 KB (W slice only)
    __shared__ int sMarr[257];
    __shared__ unsigned int sssum[257];
    const int tid = threadIdx.x;
    const int lane = tid & 63;
    const int w = tid >> 6;
    const int jg = blockIdx.x >> 3;
    const int dom = blockIdx.x & 7;
    const int j0 = jg * 16;

    // stage W_hh slice (rows: r gate j0..+15, z, n), f32 -> bf16, XOR swizzle
    for (int e = tid; e < 48 * 512; e += 256) {
        int rrow = e >> 9;
        int col = e & 511;
        int gate = rrow >> 4;
        int jl = rrow & 15;
        float v = Whh[((long)(gate * 512 + j0 + jl)) * 512 + col];
        int byteo = (rrow * 1024 + col * 2) ^ ((rrow & 7) << 4);
        *(unsigned short*)((char*)ldsW + byteo) = f2bf(v);
    }
    for (int e = tid; e < 257; e += 256) { sMarr[e] = Marr[e]; sssum[e] = ssum[e]; }

    const int j = j0 + (lane & 15);
    const float bhr = bhh[j];
    const float bhz = bhh[512 + j];
    const float bhn = bhh[1024 + j];
    const int rbase = w * 16 + (lane >> 4) * 4;     // pointwise rows (local)
    const int arowl = w * 16 + (lane & 15);         // A-frag row (local)
    const int kcol0 = (lane >> 4) * 8;              // A-frag k base
    unsigned int* dmeta = meta + 64 * dom;
    __syncthreads();   // ldsW + sMarr/sssum ready

    int crec[4], nrec[4];
    unsigned short cgr[4], cgz[4], cgn[4], ngr[4], ngz[4], ngn[4];

    // initial prefetch: step 0, tile tt = dom
    {
        const int Mt0 = sMarr[0];
        const long b0 = (long)sssum[0];
#pragma unroll
        for (int q = 0; q < 4; ++q) {
            int r = dom * 64 + rbase + q;
            if (r < Mt0) {
                crec[q] = recs[r];
                const unsigned short* gp = gi + (b0 + r) * 1536 + j;
                cgr[q] = gp[0]; cgz[q] = gp[512]; cgn[q] = gp[1024];
            } else crec[q] = -1;
        }
    }

    for (int t = 0; t < 256; ++t) {
        const int Mt = sMarr[t];
        if (Mt == 0) break;
        const int ntiles = (Mt + 63) >> 6;
        if (dom >= ntiles) break;
        const unsigned short* hsrc = (t & 1) ? hstB : hstA;
        unsigned short* hdst = (t & 1) ? hstA : hstB;
        const long base = (long)sssum[t];

        for (int tt = dom; tt < ntiles; tt += 8) {
            const int r0 = tt * 64;

            // A-frags + heff straight from global (post-barrier critical path)
            const unsigned short* arowp = hsrc + ((long)(r0 + arowl)) * 512 + kcol0;
            short8 af[16];
#pragma unroll
            for (int kk = 0; kk < 16; ++kk)
                af[kk] = *(const short8*)(arowp + kk * 32);
            unsigned short he[4];
#pragma unroll
            for (int q = 0; q < 4; ++q)
                he[q] = hsrc[(long)(r0 + rbase + q) * 512 + j];

            // in-step prefetch of tile tt+8's gi/recs (overlaps MFMA below)
            const bool instep = (tt + 8 < ntiles);
            if (instep) {
#pragma unroll
                for (int q = 0; q < 4; ++q) {
                    int r = (tt + 8) * 64 + rbase + q;
                    if (r < Mt) {
                        nrec[q] = recs[r];
                        const unsigned short* gp = gi + (base + r) * 1536 + j;
                        ngr[q] = gp[0]; ngz[q] = gp[512]; ngn[q] = gp[1024];
                    } else nrec[q] = -1;
                }
            }

            f32x4 acch[3];
#pragma unroll
            for (int g = 0; g < 3; ++g) acch[g] = (f32x4){0.f, 0.f, 0.f, 0.f};

#pragma unroll
            for (int kk = 0; kk < 16; ++kk) {
#pragma unroll
                for (int g = 0; g < 3; ++g) {
                    int rrow = g * 16 + (lane & 15);
                    int bbyte = (rrow * 1024 + kk * 64 + ((lane >> 4) * 16)) ^ ((rrow & 7) << 4);
                    short8 bfrag = *(const short8*)((const char*)ldsW + bbyte);
                    acch[g] = __builtin_amdgcn_mfma_f32_16x16x32_bf16(af[kk], bfrag, acch[g], 0, 0, 0);
                }
            }

            // fused GRU pointwise + stores (uses prefetched gi regs)
#pragma unroll
            for (int q = 0; q < 4; ++q) {
                if (crec[q] >= 0) {
                    int r = r0 + rbase + q;
                    int b = crec[q] >> 16, st = crec[q] & 0xffff;
                    int s = st + t;
                    float heff = bf2f(he[q]);
                    float rgt = sigm(bf2f(cgr[q]) + acch[0][q] + bhr);
                    float zgt = sigm(bf2f(cgz[q]) + acch[1][q] + bhz);
                    float ngt = tanh_fast(bf2f(cgn[q]) + rgt * (acch[2][q] + bhn));
                    float hnew = (1.f - zgt) * ngt + zgt * heff;
                    unsigned short hb16 = f2bf(hnew);
                    hdst[(long)r * 512 + j] = hb16;
                    rnn[((long)(b * 256 + s)) * 512 + j] = hb16;
                    if (s == 255) hid_out[b * 512 + j] = hnew;
                }
            }
            if (instep) {
#pragma unroll
                for (int q = 0; q < 4; ++q) {
                    crec[q] = nrec[q]; cgr[q] = ngr[q]; cgz[q] = ngz[q]; cgn[q] = ngn[q];
                }
            }
        }

        // pre-barrier prefetch: NEXT step's first tile (tt = dom) gi/recs.
        // Addresses are h-independent; loads complete during the barrier wait.
        {
            const int Mt1 = sMarr[t + 1];
            if (Mt1 > 0 && dom < ((Mt1 + 63) >> 6)) {
                const long b1 = (long)sssum[t + 1];
#pragma unroll
                for (int q = 0; q < 4; ++q) {
                    int r = dom * 64 + rbase + q;
                    if (r < Mt1) {
                        crec[q] = recs[r];
                        const unsigned short* gp = gi + (b1 + r) * 1536 + j;
                        cgr[q] = gp[0]; cgz[q] = gp[512]; cgn[q] = gp[1024];
                    } else crec[q] = -1;
                }
            }
        }
        dbar(dmeta, (unsigned int)t);
    }
}

// ---------------------------------------------------------------------------
// Q head (unchanged)
// ---------------------------------------------------------------------------
__global__ __launch_bounds__(256) void qhead(
    const unsigned short* __restrict__ rnn, const float* __restrict__ Wq,
    const float* __restrict__ bq, const int* __restrict__ avail,
    float* __restrict__ qout)
{
    const int w = threadIdx.x >> 6;
    const int lane = threadIdx.x & 63;
    const long row = (long)blockIdx.x * 4 + w;
    const int a = lane & 15;
    const int kc = lane >> 4;
    const unsigned short* hr = rnn + row * H + kc * 128;
    const float* wr = Wq + a * H + kc * 128;
    float sum = 0.f;
#pragma unroll
    for (int i = 0; i < 128; i += 8) {
        short8 hv = *(const short8*)(hr + i);
        float4 wa = *(const float4*)(wr + i);
        float4 wb = *(const float4*)(wr + i + 4);
        sum += bf2f((unsigned short)hv[0]) * wa.x;
        sum += bf2f((unsigned short)hv[1]) * wa.y;
        sum += bf2f((unsigned short)hv[2]) * wa.z;
        sum += bf2f((unsigned short)hv[3]) * wa.w;
        sum += bf2f((unsigned short)hv[4]) * wb.x;
        sum += bf2f((unsigned short)hv[5]) * wb.y;
        sum += bf2f((unsigned short)hv[6]) * wb.z;
        sum += bf2f((unsigned short)hv[7]) * wb.w;
    }
    sum += __shfl_xor(sum, 16);
    sum += __shfl_xor(sum, 32);
    if (kc == 0) {
        float qv = sum + bq[a];
        int av = avail[row * 16 + a];
        if (av == 0) qv -= 1e10f;
        qout[row * 16 + a] = qv;
    }
}

// ---------------------------------------------------------------------------
extern "C" void kernel_launch(void* const* d_in, const int* in_sizes, int n_in,
                              void* d_out, int out_size, void* d_ws, size_t ws_size,
                              hipStream_t stream)
{
    const float* hidden = (const float*)d_in[0];
    const float* x      = (const float*)d_in[1];
    const int*   dones  = (const int*)d_in[2];
    const int*   avail  = (const int*)d_in[3];
    const float* Wl     = (const float*)d_in[4];
    const float* bl     = (const float*)d_in[5];
    const float* ln_g   = (const float*)d_in[6];
    const float* ln_b   = (const float*)d_in[7];
    const float* W_ih   = (const float*)d_in[8];
    const float* W_hh   = (const float*)d_in[9];
    const float* b_ih   = (const float*)d_in[10];
    const float* b_hh   = (const float*)d_in[11];
    const float* Wq     = (const float*)d_in[12];
    const float* bq     = (const float*)d_in[13];

    char* p = (char*)d_ws;
    unsigned short* actA = (unsigned short*)p;                // 16 MB; hst0 after gi GEMM
    unsigned short* hst0 = actA;
    p += (size_t)NROWS * H * 2;
    unsigned short* actB = (unsigned short*)p;                // gi overlays actB+gout (48 MB)
    unsigned short* gi   = actB;
    p += (size_t)NROWS * H * 2;                               // 16 MB
    p += (size_t)NROWS * H * 4;                               // 32 MB (gi tail region)
    unsigned short* rnn  = (unsigned short*)p; p += (size_t)NROWS * H * 2;  // 16 MB
    char* wreg = p;                                           // weights region (hst1 overlay)
    unsigned short* wlb  = (unsigned short*)wreg;             // 2 MB
    unsigned short* wihb = (unsigned short*)(wreg + (size_t)4 * H * H * 2); // 1.5 MB
    unsigned short* hst1 = (unsigned short*)wreg;             // 16 MB (after gi GEMM)
    p += (size_t)NROWS * H * 2;
    int* lenArr = (int*)p;          p += (size_t)NROWS * 4;   // 64 KB
    int* recs   = (int*)p;          p += (size_t)NROWS * 4;   // 64 KB
    int* pmap   = (int*)p;          p += (size_t)NROWS * 4;   // 64 KB
    unsigned int* meta = (unsigned int*)p;  p += 8192;        // 2048 u32, ALL zeroed
    unsigned int* hist = meta + 512;
    unsigned int* offs = meta + 784;
    int* Marr = (int*)(meta + 1056);
    unsigned int* ssum = meta + 1328;

    // 1) convert inputs to bf16; zero meta
    cvt_init<<<9984, 256, 0, stream>>>(x, Wl, W_ih, actA, wlb, wihb, meta);

    // 2) segment machinery
    seg_build<<<64, 256, 0, stream>>>(dones, lenArr, hist);
    seg_offsets<<<1, 256, 0, stream>>>(hist, Marr, offs, ssum);
    seg_scatter<<<64, 256, 0, stream>>>(lenArr, offs, recs);
    pmap_build<<<64, 256, 0, stream>>>(recs, Marr, ssum, lenArr, pmap);

    // 3) MLP stack: 4 x fused GEMM+LN+ReLU (bf16 -> bf16, no f32 round-trip)
    unsigned short* cur = actA;
    unsigned short* nxt = actB;
    for (int l = 0; l < 4; ++l) {
        gemm_ln<<<256, 256, 0, stream>>>(cur, wlb + (size_t)l * H * H, bl + l * H,
                                         ln_g + l * H, ln_b + l * H, nxt);
        unsigned short* tsw = cur; cur = nxt; nxt = tsw;
    }
    // cur == actA

    // 4) gi = act @ W_ih^T + b_ih -> bf16, ROW-PERMUTED by pmap
    gemm_bt<<<1536, 256, 0, stream>>>(cur, wihb, b_ih, gi, NROWS, 3 * H, H, pmap);

    // 5) init h_state rows by rank (overlays actA, free after gi GEMM)
    h_init<<<4096, 256, 0, stream>>>(recs, Marr, dones, hidden, hst0);

    // 6) segment-parallel GRU scan (8 independent 32-WG domains, gi prefetch)
    gru_seg_scan<<<256, 256, 0, stream>>>(gi, W_hh, b_hh, Marr, ssum, recs,
                                          hst0, hst1, rnn, (float*)d_out, meta);

    // 7) Q head + availability mask
    qhead<<<4096, 256, 0, stream>>>(rnn, Wq, bq, avail, (float*)d_out + BATCH * H);
}

// Round 7
// 584.279 us; speedup vs baseline: 1.6393x; 1.3887x over previous
//
#include <hip/hip_runtime.h>
#include <hip/hip_bf16.h>

typedef short short8 __attribute__((ext_vector_type(8)));
typedef float f32x4 __attribute__((ext_vector_type(4)));

#define H 512
#define BATCH 64
#define SEQ 256
#define NROWS 16384   // BATCH*SEQ
#define NDOM 16       // domains (2 per XCD), 16 WGs each

__device__ __forceinline__ float bf2f(unsigned short u) {
    union { unsigned int i; float f; } v;
    v.i = ((unsigned int)u) << 16;
    return v.f;
}
__device__ __forceinline__ unsigned short f2bf(float f) {
    union { float f; unsigned int i; } v;
    v.f = f;
    unsigned int lsb = (v.i >> 16) & 1u;
    v.i += 0x7fffu + lsb;   // round-to-nearest-even
    return (unsigned short)(v.i >> 16);
}
__device__ __forceinline__ float sigm(float x) { return 1.f / (1.f + __expf(-x)); }
__device__ __forceinline__ float tanh_fast(float x) { return 2.f / (1.f + __expf(-2.f * x)) - 1.f; }

// ---------------------------------------------------------------------------
// convert + init: x->bf16, Wl->bf16, W_ih->bf16; zero meta region (2560 u32)
// ---------------------------------------------------------------------------
__global__ __launch_bounds__(256) void cvt_init(
    const float* __restrict__ x, const float* __restrict__ Wl,
    const float* __restrict__ Wih,
    unsigned short* __restrict__ actA, unsigned short* __restrict__ wlb,
    unsigned short* __restrict__ wihb, unsigned int* __restrict__ meta)
{
    long idx4 = (long)blockIdx.x * 256 + threadIdx.x;
    if (idx4 < 2560) meta[idx4] = 0u;
    long i = idx4 * 4;
    const long N1 = 8388608;            // x: 16384*512
    const long N2 = N1 + 1048576;       // Wl: 4*512*512
    const long N3 = N2 + 786432;        // W_ih: 1536*512
    const float* src; unsigned short* dst; long off;
    if (i < N1)      { src = x;   dst = actA; off = i; }
    else if (i < N2) { src = Wl;  dst = wlb;  off = i - N1; }
    else if (i < N3) { src = Wih; dst = wihb; off = i - N2; }
    else return;
    float4 v = *(const float4*)(src + off);
    ushort4 o;
    o.x = f2bf(v.x); o.y = f2bf(v.y); o.z = f2bf(v.z); o.w = f2bf(v.w);
    *(ushort4*)(dst + off) = o;
}

// ---------------------------------------------------------------------------
// Segment machinery (unchanged from r6)
// ---------------------------------------------------------------------------
__global__ __launch_bounds__(256) void seg_build(
    const int* __restrict__ dones, int* __restrict__ lenArr,
    unsigned int* __restrict__ hist)
{
    __shared__ int d[256];
    const int b = blockIdx.x, s = threadIdx.x;
    d[s] = dones[b * 256 + s];
    __syncthreads();
    int len = 0;
    bool start = (s == 0) || (d[s] != 0);
    if (start) {
        len = 1;
        while (s + len < 256 && d[s + len] == 0) len++;
        atomicAdd(&hist[len], 1u);
    }
    lenArr[b * 256 + s] = len;
}

__global__ __launch_bounds__(256) void seg_offsets(
    const unsigned int* __restrict__ hist, int* __restrict__ Marr,
    unsigned int* __restrict__ offs, unsigned int* __restrict__ ssum)
{
    __shared__ unsigned int h[257];
    __shared__ int Msh[257];
    const int t = threadIdx.x;
    h[t] = hist[t];
    if (t == 0) h[256] = hist[256];
    __syncthreads();
    for (int tt = t; tt <= 256; tt += 256) {
        unsigned int m = 0;
        for (int L = tt + 1; L <= 256; ++L) m += h[L];
        Marr[tt] = (int)m;
        offs[tt] = m;
        Msh[tt] = (int)m;
    }
    __syncthreads();
    if (t == 0) {
        unsigned int acc = 0;
        for (int k = 0; k <= 256; ++k) { ssum[k] = acc; acc += (unsigned int)Msh[k]; }
    }
}

__global__ __launch_bounds__(256) void seg_scatter(
    const int* __restrict__ lenArr, unsigned int* __restrict__ offs,
    int* __restrict__ recs)
{
    const int b = blockIdx.x, s = threadIdx.x;
    int len = lenArr[b * 256 + s];
    if (len > 0) {
        unsigned int pos = atomicAdd(&offs[len], 1u);
        recs[pos] = (b << 16) | s;
    }
}

__global__ __launch_bounds__(256) void pmap_build(
    const int* __restrict__ recs, const int* __restrict__ Marr,
    const unsigned int* __restrict__ ssum, const int* __restrict__ lenArr,
    int* __restrict__ pmap)
{
    const int i = blockIdx.x * 256 + threadIdx.x;
    if (i >= Marr[0]) return;
    int rec = recs[i];
    int b = rec >> 16, st = rec & 0xffff;
    int len = lenArr[b * 256 + st];
    for (int t = 0; t < len; ++t) pmap[b * 256 + st + t] = (int)ssum[t] + i;
}

__global__ __launch_bounds__(256) void h_init(
    const int* __restrict__ recs, const int* __restrict__ Marr,
    const int* __restrict__ dones, const float* __restrict__ hidden,
    unsigned short* __restrict__ hst)
{
    const int w = threadIdx.x >> 6, lane = threadIdx.x & 63;
    const int i = blockIdx.x * 4 + w;
    const int nseg = Marr[0];
    const int c0 = lane * 8;
    unsigned short* dst = hst + (long)i * 512 + c0;
    if (i < nseg) {
        int rec = recs[i];
        int b = rec >> 16, st = rec & 0xffff;
        if (st == 0 && dones[b * 256] == 0) {
            float4 va = *(const float4*)(hidden + b * 512 + c0);
            float4 vb = *(const float4*)(hidden + b * 512 + c0 + 4);
            ushort4 o0 = {f2bf(va.x), f2bf(va.y), f2bf(va.z), f2bf(va.w)};
            ushort4 o1 = {f2bf(vb.x), f2bf(vb.y), f2bf(vb.z), f2bf(vb.w)};
            *(ushort4*)dst = o0; *(ushort4*)(dst + 4) = o1;
            return;
        }
    }
    ushort4 z4 = {0, 0, 0, 0};
    *(ushort4*)dst = z4; *(ushort4*)(dst + 4) = z4;
}

// ---------------------------------------------------------------------------
// Fused MLP layer: out = relu(LN(A @ W^T + bias)) in bf16 (unchanged from r6)
// ---------------------------------------------------------------------------
__global__ __launch_bounds__(256) void gemm_ln(
    const unsigned short* __restrict__ A,
    const unsigned short* __restrict__ W,
    const float* __restrict__ bias, const float* __restrict__ g,
    const float* __restrict__ b, unsigned short* __restrict__ Out)
{
    __shared__ unsigned short ldsA[64 * 64];
    __shared__ unsigned short ldsW[512 * 64];
    __shared__ float red[64 * 8];
    const int tid = threadIdx.x;
    const int lane = tid & 63;
    const int w = tid >> 6;
    const long m0 = (long)blockIdx.x * 64;

    f32x4 acc[4][8];
#pragma unroll
    for (int i = 0; i < 4; ++i)
#pragma unroll
        for (int jn = 0; jn < 8; ++jn) acc[i][jn] = (f32x4){0.f, 0.f, 0.f, 0.f};

    for (int kt = 0; kt < 512; kt += 64) {
        __syncthreads();
#pragma unroll
        for (int i = 0; i < 2; ++i) {
            int o = (i * 256 + tid) * 16;
            int row = o >> 7;
            int ch = (o & 127) >> 4;
            long gcol = (long)kt * 2 + (long)((ch ^ (row & 7)) << 4);
            __builtin_amdgcn_global_load_lds(
                (const unsigned int*)((const char*)A + (m0 + row) * 1024 + gcol),
                (unsigned int*)(ldsA + (i * 256 + w * 64) * 8), 16, 0, 0);
        }
#pragma unroll
        for (int i = 0; i < 16; ++i) {
            int o = (i * 256 + tid) * 16;
            int row = o >> 7;
            int ch = (o & 127) >> 4;
            long gcol = (long)kt * 2 + (long)((ch ^ (row & 7)) << 4);
            __builtin_amdgcn_global_load_lds(
                (const unsigned int*)((const char*)W + (long)row * 1024 + gcol),
                (unsigned int*)(ldsW + (i * 256 + w * 64) * 8), 16, 0, 0);
        }
        __syncthreads();

#pragma unroll
        for (int k2 = 0; k2 < 2; ++k2) {
            short8 af[4], bfr[8];
#pragma unroll
            for (int i = 0; i < 4; ++i) {
                int row = i * 16 + (lane & 15);
                int byteo = (row * 128 + k2 * 64 + ((lane >> 4) * 16)) ^ ((row & 7) << 4);
                af[i] = *(const short8*)((const char*)ldsA + byteo);
            }
#pragma unroll
            for (int jn = 0; jn < 8; ++jn) {
                int row = w * 128 + jn * 16 + (lane & 15);
                int byteo = (row * 128 + k2 * 64 + ((lane >> 4) * 16)) ^ ((row & 7) << 4);
                bfr[jn] = *(const short8*)((const char*)ldsW + byteo);
            }
#pragma unroll
            for (int i = 0; i < 4; ++i)
#pragma unroll
                for (int jn = 0; jn < 8; ++jn)
                    acc[i][jn] = __builtin_amdgcn_mfma_f32_16x16x32_bf16(af[i], bfr[jn], acc[i][jn], 0, 0, 0);
        }
    }

    float bz[8], gl[8], bl2[8];
#pragma unroll
    for (int jn = 0; jn < 8; ++jn) {
        int n = w * 128 + jn * 16 + (lane & 15);
        bz[jn] = bias[n]; gl[jn] = g[n]; bl2[jn] = b[n];
    }
#pragma unroll
    for (int i = 0; i < 4; ++i)
#pragma unroll
        for (int jn = 0; jn < 8; ++jn)
#pragma unroll
            for (int r = 0; r < 4; ++r) acc[i][jn][r] += bz[jn];

#pragma unroll
    for (int i = 0; i < 4; ++i) {
#pragma unroll
        for (int r = 0; r < 4; ++r) {
            float sv = 0.f, qv = 0.f;
#pragma unroll
            for (int jn = 0; jn < 8; ++jn) {
                float v = acc[i][jn][r];
                sv += v; qv += v * v;
            }
            sv += __shfl_xor(sv, 1); qv += __shfl_xor(qv, 1);
            sv += __shfl_xor(sv, 2); qv += __shfl_xor(qv, 2);
            sv += __shfl_xor(sv, 4); qv += __shfl_xor(qv, 4);
            sv += __shfl_xor(sv, 8); qv += __shfl_xor(qv, 8);
            if ((lane & 15) == 0) {
                int row = i * 16 + (lane >> 4) * 4 + r;
                red[row * 8 + w * 2] = sv;
                red[row * 8 + w * 2 + 1] = qv;
            }
        }
    }
    __syncthreads();

#pragma unroll
    for (int i = 0; i < 4; ++i) {
#pragma unroll
        for (int r = 0; r < 4; ++r) {
            int row = i * 16 + (lane >> 4) * 4 + r;
            float s_tot = red[row * 8 + 0] + red[row * 8 + 2] + red[row * 8 + 4] + red[row * 8 + 6];
            float q_tot = red[row * 8 + 1] + red[row * 8 + 3] + red[row * 8 + 5] + red[row * 8 + 7];
            float mu = s_tot * (1.f / 512.f);
            float var = q_tot * (1.f / 512.f) - mu * mu;
            float rs = rsqrtf(var + 1e-5f);
#pragma unroll
            for (int jn = 0; jn < 8; ++jn) {
                int n = w * 128 + jn * 16 + (lane & 15);
                float v = fmaxf(0.f, (acc[i][jn][r] - mu) * rs * gl[jn] + bl2[jn]);
                Out[(m0 + row) * 512 + n] = f2bf(v);
            }
        }
    }
}

// ---------------------------------------------------------------------------
// GEMM (for gi): C = A * Bw^T + bias, row-permuted bf16 out (unchanged)
// ---------------------------------------------------------------------------
__global__ __launch_bounds__(256) void gemm_bt(
    const unsigned short* __restrict__ A, const unsigned short* __restrict__ Bw,
    const float* __restrict__ bias, unsigned short* __restrict__ Cout,
    int M, int N, int K, const int* __restrict__ rowmap)
{
    __shared__ unsigned short ldsA[128 * 64];
    __shared__ unsigned short ldsB[128 * 64];
    const int tid = threadIdx.x;
    const int lane = tid & 63;
    const int w = tid >> 6;
    const int nbx = N >> 7;
    const int bm = blockIdx.x / nbx;
    const int bn = blockIdx.x % nbx;
    const long m0 = (long)bm * 128;
    const long n0 = (long)bn * 128;
    const long Kb = (long)K * 2;

    f32x4 acc[4][4];
#pragma unroll
    for (int i = 0; i < 4; ++i)
#pragma unroll
        for (int j = 0; j < 4; ++j) acc[i][j] = (f32x4){0.f, 0.f, 0.f, 0.f};

    for (int kt = 0; kt < K; kt += 64) {
        __syncthreads();
#pragma unroll
        for (int i = 0; i < 4; ++i) {
            int o   = (i * 256 + tid) * 16;
            int row = o >> 7;
            int ch  = (o & 127) >> 4;
            long gcol = (long)kt * 2 + (long)((ch ^ (row & 7)) << 4);
            int ldsoff = (i * 256 + w * 64) * 8;
            __builtin_amdgcn_global_load_lds(
                (const unsigned int*)((const char*)A + (m0 + row) * Kb + gcol),
                (unsigned int*)(ldsA + ldsoff), 16, 0, 0);
            __builtin_amdgcn_global_load_lds(
                (const unsigned int*)((const char*)Bw + (n0 + row) * Kb + gcol),
                (unsigned int*)(ldsB + ldsoff), 16, 0, 0);
        }
        __syncthreads();

#pragma unroll
        for (int k2 = 0; k2 < 2; ++k2) {
            short8 af[4], bfr[4];
#pragma unroll
            for (int i = 0; i < 4; ++i) {
                int row = (w >> 1) * 64 + i * 16 + (lane & 15);
                int byteo = (row * 128 + k2 * 64 + ((lane >> 4) * 16)) ^ ((row & 7) << 4);
                af[i] = *(const short8*)((const char*)ldsA + byteo);
            }
#pragma unroll
            for (int j = 0; j < 4; ++j) {
                int row = (w & 1) * 64 + j * 16 + (lane & 15);
                int byteo = (row * 128 + k2 * 64 + ((lane >> 4) * 16)) ^ ((row & 7) << 4);
                bfr[j] = *(const short8*)((const char*)ldsB + byteo);
            }
#pragma unroll
            for (int i = 0; i < 4; ++i)
#pragma unroll
                for (int j = 0; j < 4; ++j)
                    acc[i][j] = __builtin_amdgcn_mfma_f32_16x16x32_bf16(af[i], bfr[j], acc[i][j], 0, 0, 0);
        }
    }

#pragma unroll
    for (int j = 0; j < 4; ++j) {
        long n = n0 + (w & 1) * 64 + j * 16 + (lane & 15);
        float bz = bias ? bias[n] : 0.f;
#pragma unroll
        for (int i = 0; i < 4; ++i) {
#pragma unroll
            for (int r = 0; r < 4; ++r) {
                long m = m0 + (w >> 1) * 64 + i * 16 + (lane >> 4) * 4 + r;
                long mm = rowmap ? (long)rowmap[m] : m;
                Cout[mm * N + n] = f2bf(acc[i][j][r] + bz);
            }
        }
    }
}

// ---------------------------------------------------------------------------
// RELAXED domain barrier: 16 WGs of one domain (same XCD by %8 round-robin).
// No acquire/release -> no buffer_inv / buffer_wbl2 cache maintenance.
// Ordering: __syncthreads drains vmcnt(0) (stores in shared XCD L2 via
// write-through L1); readers bypass L1 with sc0 loads (see scan kernel).
// ---------------------------------------------------------------------------
__device__ __forceinline__ void dbar(unsigned int* __restrict__ dm,
                                     unsigned int epoch)
{
    __syncthreads();   // emits s_waitcnt vmcnt(0) per wave before s_barrier
    if (threadIdx.x == 0) {
        unsigned int p = __hip_atomic_fetch_add(&dm[0], 1u, __ATOMIC_RELAXED,
                                                __HIP_MEMORY_SCOPE_AGENT);
        if (p == (epoch + 1u) * 16u - 1u) {
            __hip_atomic_store(&dm[16], epoch + 1u, __ATOMIC_RELAXED,
                               __HIP_MEMORY_SCOPE_AGENT);
        } else {
            while (__hip_atomic_load(&dm[16], __ATOMIC_RELAXED,
                                     __HIP_MEMORY_SCOPE_AGENT) <= epoch)
                __builtin_amdgcn_s_sleep(2);
        }
    }
    __syncthreads();
    __builtin_amdgcn_sched_barrier(0);   // no code crosses the barrier
}

// ---------------------------------------------------------------------------
// Segment-parallel GRU scan: 16 domains x 16 WGs (2 domains per XCD).
// WG = (jg, dom): jg owns 32 output cols (96-row W_hh slice, 96KB LDS);
// tile tt (64 ranks) owned by dom = tt%16 forever. Cross-WG h reads use
// inline-asm sc0 loads (L1 bypass; L2 is the intra-XCD coherence point).
// ---------------------------------------------------------------------------
__global__ __launch_bounds__(256, 1) void gru_seg_scan(
    const unsigned short* __restrict__ gi,   // [16384,1536] bf16, rank-permuted
    const float* __restrict__ Whh,           // [1536,512] f32
    const float* __restrict__ bhh,           // [1536] f32
    const int* __restrict__ Marr,
    const unsigned int* __restrict__ ssum,
    const int* __restrict__ recs,
    unsigned short* __restrict__ hstA,       // by rank, read when t even
    unsigned short* __restrict__ hstB,
    unsigned short* __restrict__ rnn,
    float* __restrict__ hid_out,
    unsigned int* __restrict__ meta)
{
    __shared__ unsigned short ldsW[96 * 512];   // 96 KB (3 gates x 32 cols)
    __shared__ int sMarr[257];
    __shared__ unsigned int sssum[257];
    const int tid = threadIdx.x;
    const int lane = tid & 63;
    const int w = tid >> 6;
    const int jg = blockIdx.x >> 4;             // 0..15
    const int dom = blockIdx.x & 15;            // 0..15 (XCD = dom & 7)
    const int j0 = jg * 32;

    // stage W_hh slice: rrow = gate*32 + jl, f32 -> bf16, XOR swizzle
    for (int e = tid; e < 96 * 512; e += 256) {
        int rrow = e >> 9;
        int col = e & 511;
        int gate = rrow >> 5;
        int jl = rrow & 31;
        float v = Whh[((long)(gate * 512 + j0 + jl)) * 512 + col];
        int byteo = (rrow * 1024 + col * 2) ^ ((rrow & 7) << 4);
        *(unsigned short*)((char*)ldsW + byteo) = f2bf(v);
    }
    for (int e = tid; e < 257; e += 256) { sMarr[e] = Marr[e]; sssum[e] = ssum[e]; }

    const int jl16 = lane & 15;
    float bhr[2], bhz[2], bhn[2];
#pragma unroll
    for (int jj = 0; jj < 2; ++jj) {
        int jc = j0 + jj * 16 + jl16;
        bhr[jj] = bhh[jc]; bhz[jj] = bhh[512 + jc]; bhn[jj] = bhh[1024 + jc];
    }
    const int rbase = w * 16 + (lane >> 4) * 4;     // pointwise rows (local)
    const int arowl = w * 16 + jl16;                // A-frag row (local)
    const int kcol0 = (lane >> 4) * 8;              // A-frag k base
    unsigned int* dmeta = meta + 64 * dom;
    __syncthreads();   // ldsW + sMarr/sssum ready

    int crec[4], nrec[4];
    unsigned short cgr[4][2], cgz[4][2], cgn[4][2];
    unsigned short ngr[4][2], ngz[4][2], ngn[4][2];

    // initial prefetch: step 0, tile tt = dom (plain loads; gi is pre-kernel data)
    {
        const int Mt0 = sMarr[0];
        const long b0 = (long)sssum[0];
#pragma unroll
        for (int q = 0; q < 4; ++q) {
            int r = dom * 64 + rbase + q;
            if (r < Mt0) {
                crec[q] = recs[r];
#pragma unroll
                for (int jj = 0; jj < 2; ++jj) {
                    const unsigned short* gp = gi + (b0 + r) * 1536 + j0 + jj * 16 + jl16;
                    cgr[q][jj] = gp[0]; cgz[q][jj] = gp[512]; cgn[q][jj] = gp[1024];
                }
            } else crec[q] = -1;
        }
    }

    for (int t = 0; t < 256; ++t) {
        const int Mt = sMarr[t];
        if (Mt == 0) break;
        const int ntiles = (Mt + 63) >> 6;
        if (dom >= ntiles) break;
        const unsigned short* hsrc = (t & 1) ? hstB : hstA;
        unsigned short* hdst = (t & 1) ? hstA : hstB;
        const long base = (long)sssum[t];

        for (int tt = dom; tt < ntiles; tt += NDOM) {
            const int r0 = tt * 64;

            // --- cross-WG h reads: sc0 (L1-bypass) asm loads ---
            const unsigned short* arowp = hsrc + ((long)(r0 + arowl)) * 512 + kcol0;
            short8 af[16];
#pragma unroll
            for (int kk = 0; kk < 16; ++kk) {
                const unsigned short* ap = arowp + kk * 32;
                asm volatile("global_load_dwordx4 %0, %1, off sc0"
                             : "=v"(af[kk]) : "v"(ap));
            }
            unsigned int hu[4][2];
#pragma unroll
            for (int q = 0; q < 4; ++q)
#pragma unroll
                for (int jj = 0; jj < 2; ++jj) {
                    const unsigned short* hp = hsrc + (long)(r0 + rbase + q) * 512
                                             + j0 + jj * 16 + jl16;
                    asm volatile("global_load_ushort %0, %1, off sc0"
                                 : "=v"(hu[q][jj]) : "v"(hp));
                }
            asm volatile("s_waitcnt vmcnt(0)" ::: "memory");
            __builtin_amdgcn_sched_barrier(0);

            // in-step prefetch of tile tt+16's gi/recs (plain; overlaps MFMA)
            const bool instep = (tt + NDOM < ntiles);
            if (instep) {
#pragma unroll
                for (int q = 0; q < 4; ++q) {
                    int r = (tt + NDOM) * 64 + rbase + q;
                    if (r < Mt) {
                        nrec[q] = recs[r];
#pragma unroll
                        for (int jj = 0; jj < 2; ++jj) {
                            const unsigned short* gp = gi + (base + r) * 1536 + j0 + jj * 16 + jl16;
                            ngr[q][jj] = gp[0]; ngz[q][jj] = gp[512]; ngn[q][jj] = gp[1024];
                        }
                    } else nrec[q] = -1;
                }
            }

            f32x4 acch[3][2];
#pragma unroll
            for (int g = 0; g < 3; ++g)
#pragma unroll
                for (int jj = 0; jj < 2; ++jj) acch[g][jj] = (f32x4){0.f, 0.f, 0.f, 0.f};

#pragma unroll
            for (int kk = 0; kk < 16; ++kk) {
#pragma unroll
                for (int g = 0; g < 3; ++g)
#pragma unroll
                    for (int jj = 0; jj < 2; ++jj) {
                        int rrow = g * 32 + jj * 16 + jl16;
                        int bbyte = (rrow * 1024 + kk * 64 + ((lane >> 4) * 16)) ^ ((rrow & 7) << 4);
                        short8 bfrag = *(const short8*)((const char*)ldsW + bbyte);
                        acch[g][jj] = __builtin_amdgcn_mfma_f32_16x16x32_bf16(af[kk], bfrag, acch[g][jj], 0, 0, 0);
                    }
            }

            // fused GRU pointwise + stores
#pragma unroll
            for (int q = 0; q < 4; ++q) {
                if (crec[q] >= 0) {
                    int r = r0 + rbase + q;
                    int b = crec[q] >> 16, st = crec[q] & 0xffff;
                    int s = st + t;
#pragma unroll
                    for (int jj = 0; jj < 2; ++jj) {
                        int jc = j0 + jj * 16 + jl16;
                        float heff = bf2f((unsigned short)hu[q][jj]);
                        float rgt = sigm(bf2f(cgr[q][jj]) + acch[0][jj][q] + bhr[jj]);
                        float zgt = sigm(bf2f(cgz[q][jj]) + acch[1][jj][q] + bhz[jj]);
                        float ngt = tanh_fast(bf2f(cgn[q][jj]) + rgt * (acch[2][jj][q] + bhn[jj]));
                        float hnew = (1.f - zgt) * ngt + zgt * heff;
                        unsigned short hb16 = f2bf(hnew);
                        hdst[(long)r * 512 + jc] = hb16;
                        rnn[((long)(b * 256 + s)) * 512 + jc] = hb16;
                        if (s == 255) hid_out[b * 512 + jc] = hnew;
                    }
                }
            }
            if (instep) {
#pragma unroll
                for (int q = 0; q < 4; ++q) {
                    crec[q] = nrec[q];
#pragma unroll
                    for (int jj = 0; jj < 2; ++jj) {
                        cgr[q][jj] = ngr[q][jj]; cgz[q][jj] = ngz[q][jj]; cgn[q][jj] = ngn[q][jj];
                    }
                }
            }
        }

        // pre-barrier prefetch: NEXT step's first tile gi/recs (h-independent)
        {
            const int Mt1 = sMarr[t + 1];
            if (Mt1 > 0 && dom < ((Mt1 + 63) >> 6)) {
                const long b1 = (long)sssum[t + 1];
#pragma unroll
                for (int q = 0; q < 4; ++q) {
                    int r = dom * 64 + rbase + q;
                    if (r < Mt1) {
                        crec[q] = recs[r];
#pragma unroll
                        for (int jj = 0; jj < 2; ++jj) {
                            const unsigned short* gp = gi + (b1 + r) * 1536 + j0 + jj * 16 + jl16;
                            cgr[q][jj] = gp[0]; cgz[q][jj] = gp[512]; cgn[q][jj] = gp[1024];
                        }
                    } else crec[q] = -1;
                }
            }
        }
        dbar(dmeta, (unsigned int)t);
    }
}

// ---------------------------------------------------------------------------
// Q head (unchanged)
// ---------------------------------------------------------------------------
__global__ __launch_bounds__(256) void qhead(
    const unsigned short* __restrict__ rnn, const float* __restrict__ Wq,
    const float* __restrict__ bq, const int* __restrict__ avail,
    float* __restrict__ qout)
{
    const int w = threadIdx.x >> 6;
    const int lane = threadIdx.x & 63;
    const long row = (long)blockIdx.x * 4 + w;
    const int a = lane & 15;
    const int kc = lane >> 4;
    const unsigned short* hr = rnn + row * H + kc * 128;
    const float* wr = Wq + a * H + kc * 128;
    float sum = 0.f;
#pragma unroll
    for (int i = 0; i < 128; i += 8) {
        short8 hv = *(const short8*)(hr + i);
        float4 wa = *(const float4*)(wr + i);
        float4 wb = *(const float4*)(wr + i + 4);
        sum += bf2f((unsigned short)hv[0]) * wa.x;
        sum += bf2f((unsigned short)hv[1]) * wa.y;
        sum += bf2f((unsigned short)hv[2]) * wa.z;
        sum += bf2f((unsigned short)hv[3]) * wa.w;
        sum += bf2f((unsigned short)hv[4]) * wb.x;
        sum += bf2f((unsigned short)hv[5]) * wb.y;
        sum += bf2f((unsigned short)hv[6]) * wb.z;
        sum += bf2f((unsigned short)hv[7]) * wb.w;
    }
    sum += __shfl_xor(sum, 16);
    sum += __shfl_xor(sum, 32);
    if (kc == 0) {
        float qv = sum + bq[a];
        int av = avail[row * 16 + a];
        if (av == 0) qv -= 1e10f;
        qout[row * 16 + a] = qv;
    }
}

// ---------------------------------------------------------------------------
extern "C" void kernel_launch(void* const* d_in, const int* in_sizes, int n_in,
                              void* d_out, int out_size, void* d_ws, size_t ws_size,
                              hipStream_t stream)
{
    const float* hidden = (const float*)d_in[0];
    const float* x      = (const float*)d_in[1];
    const int*   dones  = (const int*)d_in[2];
    const int*   avail  = (const int*)d_in[3];
    const float* Wl     = (const float*)d_in[4];
    const float* bl     = (const float*)d_in[5];
    const float* ln_g   = (const float*)d_in[6];
    const float* ln_b   = (const float*)d_in[7];
    const float* W_ih   = (const float*)d_in[8];
    const float* W_hh   = (const float*)d_in[9];
    const float* b_ih   = (const float*)d_in[10];
    const float* b_hh   = (const float*)d_in[11];
    const float* Wq     = (const float*)d_in[12];
    const float* bq     = (const float*)d_in[13];

    char* p = (char*)d_ws;
    unsigned short* actA = (unsigned short*)p;                // 16 MB; hst0 after gi GEMM
    unsigned short* hst0 = actA;
    p += (size_t)NROWS * H * 2;
    unsigned short* actB = (unsigned short*)p;                // gi overlays actB + next 32MB
    unsigned short* gi   = actB;
    p += (size_t)NROWS * H * 2;                               // 16 MB
    p += (size_t)NROWS * H * 4;                               // 32 MB (gi tail region)
    unsigned short* rnn  = (unsigned short*)p; p += (size_t)NROWS * H * 2;  // 16 MB
    char* wreg = p;                                           // weights region (hst1 overlay)
    unsigned short* wlb  = (unsigned short*)wreg;             // 2 MB
    unsigned short* wihb = (unsigned short*)(wreg + (size_t)4 * H * H * 2); // 1.5 MB
    unsigned short* hst1 = (unsigned short*)wreg;             // 16 MB (after gi GEMM)
    p += (size_t)NROWS * H * 2;
    int* lenArr = (int*)p;          p += (size_t)NROWS * 4;
    int* recs   = (int*)p;          p += (size_t)NROWS * 4;
    int* pmap   = (int*)p;          p += (size_t)NROWS * 4;
    unsigned int* meta = (unsigned int*)p;  p += 12288;       // 2560+ u32, zeroed
    unsigned int* hist = meta + 1024;   // doms use meta[0..1023] (16 x 64)
    unsigned int* offs = meta + 1296;
    int* Marr = (int*)(meta + 1568);
    unsigned int* ssum = meta + 1840;   // ends at 2097 < 2560

    // 1) convert inputs to bf16; zero meta (incl. 16 domain barrier slots)
    cvt_init<<<9984, 256, 0, stream>>>(x, Wl, W_ih, actA, wlb, wihb, meta);

    // 2) segment machinery
    seg_build<<<64, 256, 0, stream>>>(dones, lenArr, hist);
    seg_offsets<<<1, 256, 0, stream>>>(hist, Marr, offs, ssum);
    seg_scatter<<<64, 256, 0, stream>>>(lenArr, offs, recs);
    pmap_build<<<64, 256, 0, stream>>>(recs, Marr, ssum, lenArr, pmap);

    // 3) MLP stack: 4 x fused GEMM+LN+ReLU
    unsigned short* cur = actA;
    unsigned short* nxt = actB;
    for (int l = 0; l < 4; ++l) {
        gemm_ln<<<256, 256, 0, stream>>>(cur, wlb + (size_t)l * H * H, bl + l * H,
                                         ln_g + l * H, ln_b + l * H, nxt);
        unsigned short* tsw = cur; cur = nxt; nxt = tsw;
    }
    // cur == actA

    // 4) gi = act @ W_ih^T + b_ih -> bf16, ROW-PERMUTED by pmap
    gemm_bt<<<1536, 256, 0, stream>>>(cur, wihb, b_ih, gi, NROWS, 3 * H, H, pmap);

    // 5) init h_state rows by rank (overlays actA, free after gi GEMM)
    h_init<<<4096, 256, 0, stream>>>(recs, Marr, dones, hidden, hst0);

    // 6) segment-parallel GRU scan (16 domains x 16 WGs, relaxed barriers)
    gru_seg_scan<<<256, 256, 0, stream>>>(gi, W_hh, b_hh, Marr, ssum, recs,
                                          hst0, hst1, rnn, (float*)d_out, meta);

    // 7) Q head + availability mask
    qhead<<<4096, 256, 0, stream>>>(rnn, Wq, bq, avail, (float*)d_out + BATCH * H);
}

// Round 8
// 572.666 us; speedup vs baseline: 1.6726x; 1.0203x over previous
//
#include <hip/hip_runtime.h>
#include <hip/hip_bf16.h>

typedef short short8 __attribute__((ext_vector_type(8)));
typedef float f32x4 __attribute__((ext_vector_type(4)));

#define H 512
#define BATCH 64
#define SEQ 256
#define NROWS 16384   // BATCH*SEQ
#define NDOM 16       // scan domains, 16 WGs each
#define HSTCAP 12288  // h-state rows capacity (nseg ~8224 for this input)

__device__ __forceinline__ float bf2f(unsigned short u) {
    union { unsigned int i; float f; } v;
    v.i = ((unsigned int)u) << 16;
    return v.f;
}
__device__ __forceinline__ unsigned short f2bf(float f) {
    union { float f; unsigned int i; } v;
    v.f = f;
    unsigned int lsb = (v.i >> 16) & 1u;
    v.i += 0x7fffu + lsb;   // round-to-nearest-even
    return (unsigned short)(v.i >> 16);
}
__device__ __forceinline__ float sigm(float x) { return 1.f / (1.f + __expf(-x)); }
__device__ __forceinline__ float tanh_fast(float x) { return 2.f / (1.f + __expf(-2.f * x)) - 1.f; }

// ---------------------------------------------------------------------------
// convert weights to bf16 (Wl, W_ih); zero meta region (2560 u32)
// ---------------------------------------------------------------------------
__global__ __launch_bounds__(256) void cvt_init(
    const float* __restrict__ Wl, const float* __restrict__ Wih,
    unsigned short* __restrict__ wlb, unsigned short* __restrict__ wihb,
    unsigned int* __restrict__ meta)
{
    long idx4 = (long)blockIdx.x * 256 + threadIdx.x;
    if (idx4 < 2560) meta[idx4] = 0u;
    long i = idx4 * 4;
    const long N1 = 1048576;            // Wl: 4*512*512
    const long N2 = N1 + 786432;        // W_ih: 1536*512
    const float* src; unsigned short* dst; long off;
    if (i < N1)      { src = Wl;  dst = wlb;  off = i; }
    else if (i < N2) { src = Wih; dst = wihb; off = i - N1; }
    else return;
    float4 v = *(const float4*)(src + off);
    ushort4 o;
    o.x = f2bf(v.x); o.y = f2bf(v.y); o.z = f2bf(v.z); o.w = f2bf(v.w);
    *(ushort4*)(dst + off) = o;
}

// ---------------------------------------------------------------------------
// Segment machinery (unchanged from r7)
// ---------------------------------------------------------------------------
__global__ __launch_bounds__(256) void seg_build(
    const int* __restrict__ dones, int* __restrict__ lenArr,
    unsigned int* __restrict__ hist)
{
    __shared__ int d[256];
    const int b = blockIdx.x, s = threadIdx.x;
    d[s] = dones[b * 256 + s];
    __syncthreads();
    int len = 0;
    bool start = (s == 0) || (d[s] != 0);
    if (start) {
        len = 1;
        while (s + len < 256 && d[s + len] == 0) len++;
        atomicAdd(&hist[len], 1u);
    }
    lenArr[b * 256 + s] = len;
}

__global__ __launch_bounds__(256) void seg_offsets(
    const unsigned int* __restrict__ hist, int* __restrict__ Marr,
    unsigned int* __restrict__ offs, unsigned int* __restrict__ ssum)
{
    __shared__ unsigned int h[257];
    __shared__ int Msh[257];
    const int t = threadIdx.x;
    h[t] = hist[t];
    if (t == 0) h[256] = hist[256];
    __syncthreads();
    for (int tt = t; tt <= 256; tt += 256) {
        unsigned int m = 0;
        for (int L = tt + 1; L <= 256; ++L) m += h[L];
        Marr[tt] = (int)m;
        offs[tt] = m;
        Msh[tt] = (int)m;
    }
    __syncthreads();
    if (t == 0) {
        unsigned int acc = 0;
        for (int k = 0; k <= 256; ++k) { ssum[k] = acc; acc += (unsigned int)Msh[k]; }
    }
}

__global__ __launch_bounds__(256) void seg_scatter(
    const int* __restrict__ lenArr, unsigned int* __restrict__ offs,
    int* __restrict__ recs)
{
    const int b = blockIdx.x, s = threadIdx.x;
    int len = lenArr[b * 256 + s];
    if (len > 0) {
        unsigned int pos = atomicAdd(&offs[len], 1u);
        recs[pos] = (b << 16) | s;
    }
}

__global__ __launch_bounds__(256) void pmap_build(
    const int* __restrict__ recs, const int* __restrict__ Marr,
    const unsigned int* __restrict__ ssum, const int* __restrict__ lenArr,
    int* __restrict__ pmap)
{
    const int i = blockIdx.x * 256 + threadIdx.x;
    if (i >= Marr[0]) return;
    int rec = recs[i];
    int b = rec >> 16, st = rec & 0xffff;
    int len = lenArr[b * 256 + st];
    for (int t = 0; t < len; ++t) pmap[b * 256 + st + t] = (int)ssum[t] + i;
}

// h_state row init by rank (capacity HSTCAP rows)
__global__ __launch_bounds__(256) void h_init(
    const int* __restrict__ recs, const int* __restrict__ Marr,
    const int* __restrict__ dones, const float* __restrict__ hidden,
    unsigned short* __restrict__ hst)
{
    const int w = threadIdx.x >> 6, lane = threadIdx.x & 63;
    const int i = blockIdx.x * 4 + w;
    const int nseg = Marr[0];
    const int c0 = lane * 8;
    unsigned short* dst = hst + (long)i * 512 + c0;
    if (i < nseg) {
        int rec = recs[i];
        int b = rec >> 16, st = rec & 0xffff;
        if (st == 0 && dones[b * 256] == 0) {
            float4 va = *(const float4*)(hidden + b * 512 + c0);
            float4 vb = *(const float4*)(hidden + b * 512 + c0 + 4);
            ushort4 o0 = {f2bf(va.x), f2bf(va.y), f2bf(va.z), f2bf(va.w)};
            ushort4 o1 = {f2bf(vb.x), f2bf(vb.y), f2bf(vb.z), f2bf(vb.w)};
            *(ushort4*)dst = o0; *(ushort4*)(dst + 4) = o1;
            return;
        }
    }
    ushort4 z4 = {0, 0, 0, 0};
    *(ushort4*)dst = z4; *(ushort4*)(dst + 4) = z4;
}

// ---------------------------------------------------------------------------
// FUSED row-local pipeline: x(f32) -> [Linear+LN+ReLU]x4 -> gi = act@W_ih^T+b
// One WG owns 64 rows end-to-end. Activations live in 64KB swizzled LDS;
// only W tiles stream (L2-resident, global_load_lds w/ pre-swizzled source).
// gi written bf16, row-permuted by pmap (scan rank order).
// ---------------------------------------------------------------------------
__global__ __launch_bounds__(256) void mlp_gi(
    const float* __restrict__ x,            // [16384,512] f32
    const unsigned short* __restrict__ wlb, // [4][512][512] bf16
    const unsigned short* __restrict__ wihb,// [1536][512] bf16
    const float* __restrict__ bl,           // [4][512]
    const float* __restrict__ lng,          // [4][512]
    const float* __restrict__ lnb,          // [4][512]
    const float* __restrict__ bih,          // [1536]
    const int* __restrict__ pmap,           // [16384]
    unsigned short* __restrict__ gi)        // [16384][1536] bf16
{
    __shared__ unsigned short ldsAct[64 * 512];  // 64 KB, XOR-swizzled rows
    __shared__ unsigned short ldsW[512 * 64];    // 64 KB
    __shared__ float red[64 * 8];                // 2 KB LN cross-wave reduce
    const int tid = threadIdx.x;
    const int lane = tid & 63;
    const int w = tid >> 6;
    const long m0 = (long)blockIdx.x * 64;

    // prestage x tile: f32 -> bf16, swizzled (16B-chunk XOR within 128B blocks)
#pragma unroll
    for (int it = 0; it < 16; ++it) {
        int ch = it * 256 + tid;        // 4096 chunks of 8 elems
        int row = ch >> 6;
        int c = ch & 63;
        const float* xp = x + (m0 + row) * 512 + c * 8;
        float4 a = *(const float4*)xp;
        float4 b4 = *(const float4*)(xp + 4);
        short8 v;
        v[0] = (short)f2bf(a.x);  v[1] = (short)f2bf(a.y);
        v[2] = (short)f2bf(a.z);  v[3] = (short)f2bf(a.w);
        v[4] = (short)f2bf(b4.x); v[5] = (short)f2bf(b4.y);
        v[6] = (short)f2bf(b4.z); v[7] = (short)f2bf(b4.w);
        int byteo = (row * 1024 + c * 16) ^ ((row & 7) << 4);
        *(short8*)((char*)ldsAct + byteo) = v;
    }
    // pmap for this lane's C-fragment rows (used by gi epilogue)
    int pm[4][4];
#pragma unroll
    for (int i = 0; i < 4; ++i)
#pragma unroll
        for (int r = 0; r < 4; ++r)
            pm[i][r] = pmap[m0 + i * 16 + (lane >> 4) * 4 + r];
    __syncthreads();

    // ---- 4 MLP layers (GEMM 512x512 + bias + LN + ReLU, all in-tile) ----
    for (int l = 0; l < 4; ++l) {
        const unsigned short* W = wlb + (long)l * 512 * 512;
        f32x4 acc[4][8];
#pragma unroll
        for (int i = 0; i < 4; ++i)
#pragma unroll
            for (int jn = 0; jn < 8; ++jn) acc[i][jn] = (f32x4){0.f, 0.f, 0.f, 0.f};

        for (int kt = 0; kt < 512; kt += 64) {
            __syncthreads();
#pragma unroll
            for (int i = 0; i < 16; ++i) {
                int o = (i * 256 + tid) * 16;
                int row = o >> 7;
                int c = (o & 127) >> 4;
                long gcol = (long)kt * 2 + (long)((c ^ (row & 7)) << 4);
                __builtin_amdgcn_global_load_lds(
                    (const unsigned int*)((const char*)W + (long)row * 1024 + gcol),
                    (unsigned int*)(ldsW + (i * 256 + w * 64) * 8), 16, 0, 0);
            }
            __syncthreads();
#pragma unroll
            for (int k2 = 0; k2 < 2; ++k2) {
                short8 af[4], bfr[8];
#pragma unroll
                for (int i = 0; i < 4; ++i) {
                    int row = i * 16 + (lane & 15);
                    int byteo = (row * 1024 + kt * 2 + k2 * 64 + ((lane >> 4) * 16)) ^ ((row & 7) << 4);
                    af[i] = *(const short8*)((const char*)ldsAct + byteo);
                }
#pragma unroll
                for (int jn = 0; jn < 8; ++jn) {
                    int row = w * 128 + jn * 16 + (lane & 15);
                    int byteo = (row * 128 + k2 * 64 + ((lane >> 4) * 16)) ^ ((row & 7) << 4);
                    bfr[jn] = *(const short8*)((const char*)ldsW + byteo);
                }
#pragma unroll
                for (int i = 0; i < 4; ++i)
#pragma unroll
                    for (int jn = 0; jn < 8; ++jn)
                        acc[i][jn] = __builtin_amdgcn_mfma_f32_16x16x32_bf16(af[i], bfr[jn], acc[i][jn], 0, 0, 0);
            }
        }

        // epilogue: bias + LN + ReLU, write back to ldsAct (bf16, swizzled)
        float bz[8], gl[8], bb[8];
#pragma unroll
        for (int jn = 0; jn < 8; ++jn) {
            int n = w * 128 + jn * 16 + (lane & 15);
            bz[jn] = bl[l * 512 + n]; gl[jn] = lng[l * 512 + n]; bb[jn] = lnb[l * 512 + n];
        }
#pragma unroll
        for (int i = 0; i < 4; ++i)
#pragma unroll
            for (int jn = 0; jn < 8; ++jn)
#pragma unroll
                for (int r = 0; r < 4; ++r) acc[i][jn][r] += bz[jn];

#pragma unroll
        for (int i = 0; i < 4; ++i) {
#pragma unroll
            for (int r = 0; r < 4; ++r) {
                float sv = 0.f, qv = 0.f;
#pragma unroll
                for (int jn = 0; jn < 8; ++jn) {
                    float v = acc[i][jn][r];
                    sv += v; qv += v * v;
                }
                sv += __shfl_xor(sv, 1); qv += __shfl_xor(qv, 1);
                sv += __shfl_xor(sv, 2); qv += __shfl_xor(qv, 2);
                sv += __shfl_xor(sv, 4); qv += __shfl_xor(qv, 4);
                sv += __shfl_xor(sv, 8); qv += __shfl_xor(qv, 8);
                if ((lane & 15) == 0) {
                    int row = i * 16 + (lane >> 4) * 4 + r;
                    red[row * 8 + w * 2] = sv;
                    red[row * 8 + w * 2 + 1] = qv;
                }
            }
        }
        __syncthreads();   // publish red; also: all ldsAct reads of this layer done

#pragma unroll
        for (int i = 0; i < 4; ++i) {
#pragma unroll
            for (int r = 0; r < 4; ++r) {
                int row = i * 16 + (lane >> 4) * 4 + r;
                float s_tot = red[row * 8 + 0] + red[row * 8 + 2] + red[row * 8 + 4] + red[row * 8 + 6];
                float q_tot = red[row * 8 + 1] + red[row * 8 + 3] + red[row * 8 + 5] + red[row * 8 + 7];
                float mu = s_tot * (1.f / 512.f);
                float var = q_tot * (1.f / 512.f) - mu * mu;
                float rs = rsqrtf(var + 1e-5f);
#pragma unroll
                for (int jn = 0; jn < 8; ++jn) {
                    int col = w * 128 + jn * 16 + (lane & 15);
                    float v = fmaxf(0.f, (acc[i][jn][r] - mu) * rs * gl[jn] + bb[jn]);
                    int byteo = (row * 1024 + col * 2) ^ ((row & 7) << 4);
                    *(unsigned short*)((char*)ldsAct + byteo) = f2bf(v);
                }
            }
        }
        __syncthreads();   // new act visible before next layer
    }

    // ---- gi projection: 3 chunks of 512 output cols ----
    for (int nc = 0; nc < 3; ++nc) {
        const unsigned short* W = wihb + (long)nc * 512 * 512;
        f32x4 acc[4][8];
#pragma unroll
        for (int i = 0; i < 4; ++i)
#pragma unroll
            for (int jn = 0; jn < 8; ++jn) acc[i][jn] = (f32x4){0.f, 0.f, 0.f, 0.f};

        for (int kt = 0; kt < 512; kt += 64) {
            __syncthreads();
#pragma unroll
            for (int i = 0; i < 16; ++i) {
                int o = (i * 256 + tid) * 16;
                int row = o >> 7;
                int c = (o & 127) >> 4;
                long gcol = (long)kt * 2 + (long)((c ^ (row & 7)) << 4);
                __builtin_amdgcn_global_load_lds(
                    (const unsigned int*)((const char*)W + (long)row * 1024 + gcol),
                    (unsigned int*)(ldsW + (i * 256 + w * 64) * 8), 16, 0, 0);
            }
            __syncthreads();
#pragma unroll
            for (int k2 = 0; k2 < 2; ++k2) {
                short8 af[4], bfr[8];
#pragma unroll
                for (int i = 0; i < 4; ++i) {
                    int row = i * 16 + (lane & 15);
                    int byteo = (row * 1024 + kt * 2 + k2 * 64 + ((lane >> 4) * 16)) ^ ((row & 7) << 4);
                    af[i] = *(const short8*)((const char*)ldsAct + byteo);
                }
#pragma unroll
                for (int jn = 0; jn < 8; ++jn) {
                    int row = w * 128 + jn * 16 + (lane & 15);
                    int byteo = (row * 128 + k2 * 64 + ((lane >> 4) * 16)) ^ ((row & 7) << 4);
                    bfr[jn] = *(const short8*)((const char*)ldsW + byteo);
                }
#pragma unroll
                for (int i = 0; i < 4; ++i)
#pragma unroll
                    for (int jn = 0; jn < 8; ++jn)
                        acc[i][jn] = __builtin_amdgcn_mfma_f32_16x16x32_bf16(af[i], bfr[jn], acc[i][jn], 0, 0, 0);
            }
        }

        // epilogue: + b_ih, scatter rows by pmap
#pragma unroll
        for (int jn = 0; jn < 8; ++jn) {
            int colg = nc * 512 + w * 128 + jn * 16 + (lane & 15);
            float bz = bih[colg];
#pragma unroll
            for (int i = 0; i < 4; ++i)
#pragma unroll
                for (int r = 0; r < 4; ++r)
                    gi[(long)pm[i][r] * 1536 + colg] = f2bf(acc[i][jn][r] + bz);
        }
    }
}

// ---------------------------------------------------------------------------
// RELAXED domain barrier (unchanged from r7)
// ---------------------------------------------------------------------------
__device__ __forceinline__ void dbar(unsigned int* __restrict__ dm,
                                     unsigned int epoch)
{
    __syncthreads();
    if (threadIdx.x == 0) {
        unsigned int p = __hip_atomic_fetch_add(&dm[0], 1u, __ATOMIC_RELAXED,
                                                __HIP_MEMORY_SCOPE_AGENT);
        if (p == (epoch + 1u) * 16u - 1u) {
            __hip_atomic_store(&dm[16], epoch + 1u, __ATOMIC_RELAXED,
                               __HIP_MEMORY_SCOPE_AGENT);
        } else {
            while (__hip_atomic_load(&dm[16], __ATOMIC_RELAXED,
                                     __HIP_MEMORY_SCOPE_AGENT) <= epoch)
                __builtin_amdgcn_s_sleep(2);
        }
    }
    __syncthreads();
    __builtin_amdgcn_sched_barrier(0);
}

// ---------------------------------------------------------------------------
// Segment-parallel GRU scan (unchanged from r7): 16 domains x 16 WGs.
// ---------------------------------------------------------------------------
__global__ __launch_bounds__(256, 1) void gru_seg_scan(
    const unsigned short* __restrict__ gi,
    const float* __restrict__ Whh,
    const float* __restrict__ bhh,
    const int* __restrict__ Marr,
    const unsigned int* __restrict__ ssum,
    const int* __restrict__ recs,
    unsigned short* __restrict__ hstA,
    unsigned short* __restrict__ hstB,
    unsigned short* __restrict__ rnn,
    float* __restrict__ hid_out,
    unsigned int* __restrict__ meta)
{
    __shared__ unsigned short ldsW[96 * 512];
    __shared__ int sMarr[257];
    __shared__ unsigned int sssum[257];
    const int tid = threadIdx.x;
    const int lane = tid & 63;
    const int w = tid >> 6;
    const int jg = blockIdx.x >> 4;
    const int dom = blockIdx.x & 15;
    const int j0 = jg * 32;

    for (int e = tid; e < 96 * 512; e += 256) {
        int rrow = e >> 9;
        int col = e & 511;
        int gate = rrow >> 5;
        int jl = rrow & 31;
        float v = Whh[((long)(gate * 512 + j0 + jl)) * 512 + col];
        int byteo = (rrow * 1024 + col * 2) ^ ((rrow & 7) << 4);
        *(unsigned short*)((char*)ldsW + byteo) = f2bf(v);
    }
    for (int e = tid; e < 257; e += 256) { sMarr[e] = Marr[e]; sssum[e] = ssum[e]; }

    const int jl16 = lane & 15;
    float bhr[2], bhz[2], bhn[2];
#pragma unroll
    for (int jj = 0; jj < 2; ++jj) {
        int jc = j0 + jj * 16 + jl16;
        bhr[jj] = bhh[jc]; bhz[jj] = bhh[512 + jc]; bhn[jj] = bhh[1024 + jc];
    }
    const int rbase = w * 16 + (lane >> 4) * 4;
    const int arowl = w * 16 + jl16;
    const int kcol0 = (lane >> 4) * 8;
    unsigned int* dmeta = meta + 64 * dom;
    __syncthreads();

    int crec[4], nrec[4];
    unsigned short cgr[4][2], cgz[4][2], cgn[4][2];
    unsigned short ngr[4][2], ngz[4][2], ngn[4][2];

    {
        const int Mt0 = sMarr[0];
        const long b0 = (long)sssum[0];
#pragma unroll
        for (int q = 0; q < 4; ++q) {
            int r = dom * 64 + rbase + q;
            if (r < Mt0) {
                crec[q] = recs[r];
#pragma unroll
                for (int jj = 0; jj < 2; ++jj) {
                    const unsigned short* gp = gi + (b0 + r) * 1536 + j0 + jj * 16 + jl16;
                    cgr[q][jj] = gp[0]; cgz[q][jj] = gp[512]; cgn[q][jj] = gp[1024];
                }
            } else crec[q] = -1;
        }
    }

    for (int t = 0; t < 256; ++t) {
        const int Mt = sMarr[t];
        if (Mt == 0) break;
        const int ntiles = (Mt + 63) >> 6;
        if (dom >= ntiles) break;
        const unsigned short* hsrc = (t & 1) ? hstB : hstA;
        unsigned short* hdst = (t & 1) ? hstA : hstB;
        const long base = (long)sssum[t];

        for (int tt = dom; tt < ntiles; tt += NDOM) {
            const int r0 = tt * 64;

            const unsigned short* arowp = hsrc + ((long)(r0 + arowl)) * 512 + kcol0;
            short8 af[16];
#pragma unroll
            for (int kk = 0; kk < 16; ++kk) {
                const unsigned short* ap = arowp + kk * 32;
                asm volatile("global_load_dwordx4 %0, %1, off sc0"
                             : "=v"(af[kk]) : "v"(ap));
            }
            unsigned int hu[4][2];
#pragma unroll
            for (int q = 0; q < 4; ++q)
#pragma unroll
                for (int jj = 0; jj < 2; ++jj) {
                    const unsigned short* hp = hsrc + (long)(r0 + rbase + q) * 512
                                             + j0 + jj * 16 + jl16;
                    asm volatile("global_load_ushort %0, %1, off sc0"
                                 : "=v"(hu[q][jj]) : "v"(hp));
                }
            asm volatile("s_waitcnt vmcnt(0)" ::: "memory");
            __builtin_amdgcn_sched_barrier(0);

            const bool instep = (tt + NDOM < ntiles);
            if (instep) {
#pragma unroll
                for (int q = 0; q < 4; ++q) {
                    int r = (tt + NDOM) * 64 + rbase + q;
                    if (r < Mt) {
                        nrec[q] = recs[r];
#pragma unroll
                        for (int jj = 0; jj < 2; ++jj) {
                            const unsigned short* gp = gi + (base + r) * 1536 + j0 + jj * 16 + jl16;
                            ngr[q][jj] = gp[0]; ngz[q][jj] = gp[512]; ngn[q][jj] = gp[1024];
                        }
                    } else nrec[q] = -1;
                }
            }

            f32x4 acch[3][2];
#pragma unroll
            for (int g = 0; g < 3; ++g)
#pragma unroll
                for (int jj = 0; jj < 2; ++jj) acch[g][jj] = (f32x4){0.f, 0.f, 0.f, 0.f};

#pragma unroll
            for (int kk = 0; kk < 16; ++kk) {
#pragma unroll
                for (int g = 0; g < 3; ++g)
#pragma unroll
                    for (int jj = 0; jj < 2; ++jj) {
                        int rrow = g * 32 + jj * 16 + jl16;
                        int bbyte = (rrow * 1024 + kk * 64 + ((lane >> 4) * 16)) ^ ((rrow & 7) << 4);
                        short8 bfrag = *(const short8*)((const char*)ldsW + bbyte);
                        acch[g][jj] = __builtin_amdgcn_mfma_f32_16x16x32_bf16(af[kk], bfrag, acch[g][jj], 0, 0, 0);
                    }
            }

#pragma unroll
            for (int q = 0; q < 4; ++q) {
                if (crec[q] >= 0) {
                    int r = r0 + rbase + q;
                    int b = crec[q] >> 16, st = crec[q] & 0xffff;
                    int s = st + t;
#pragma unroll
                    for (int jj = 0; jj < 2; ++jj) {
                        int jc = j0 + jj * 16 + jl16;
                        float heff = bf2f((unsigned short)hu[q][jj]);
                        float rgt = sigm(bf2f(cgr[q][jj]) + acch[0][jj][q] + bhr[jj]);
                        float zgt = sigm(bf2f(cgz[q][jj]) + acch[1][jj][q] + bhz[jj]);
                        float ngt = tanh_fast(bf2f(cgn[q][jj]) + rgt * (acch[2][jj][q] + bhn[jj]));
                        float hnew = (1.f - zgt) * ngt + zgt * heff;
                        unsigned short hb16 = f2bf(hnew);
                        hdst[(long)r * 512 + jc] = hb16;
                        rnn[((long)(b * 256 + s)) * 512 + jc] = hb16;
                        if (s == 255) hid_out[b * 512 + jc] = hnew;
                    }
                }
            }
            if (instep) {
#pragma unroll
                for (int q = 0; q < 4; ++q) {
                    crec[q] = nrec[q];
#pragma unroll
                    for (int jj = 0; jj < 2; ++jj) {
                        cgr[q][jj] = ngr[q][jj]; cgz[q][jj] = ngz[q][jj]; cgn[q][jj] = ngn[q][jj];
                    }
                }
            }
        }

        {
            const int Mt1 = sMarr[t + 1];
            if (Mt1 > 0 && dom < ((Mt1 + 63) >> 6)) {
                const long b1 = (long)sssum[t + 1];
#pragma unroll
                for (int q = 0; q < 4; ++q) {
                    int r = dom * 64 + rbase + q;
                    if (r < Mt1) {
                        crec[q] = recs[r];
#pragma unroll
                        for (int jj = 0; jj < 2; ++jj) {
                            const unsigned short* gp = gi + (b1 + r) * 1536 + j0 + jj * 16 + jl16;
                            cgr[q][jj] = gp[0]; cgz[q][jj] = gp[512]; cgn[q][jj] = gp[1024];
                        }
                    } else crec[q] = -1;
                }
            }
        }
        dbar(dmeta, (unsigned int)t);
    }
}

// ---------------------------------------------------------------------------
// Q head (unchanged)
// ---------------------------------------------------------------------------
__global__ __launch_bounds__(256) void qhead(
    const unsigned short* __restrict__ rnn, const float* __restrict__ Wq,
    const float* __restrict__ bq, const int* __restrict__ avail,
    float* __restrict__ qout)
{
    const int w = threadIdx.x >> 6;
    const int lane = threadIdx.x & 63;
    const long row = (long)blockIdx.x * 4 + w;
    const int a = lane & 15;
    const int kc = lane >> 4;
    const unsigned short* hr = rnn + row * H + kc * 128;
    const float* wr = Wq + a * H + kc * 128;
    float sum = 0.f;
#pragma unroll
    for (int i = 0; i < 128; i += 8) {
        short8 hv = *(const short8*)(hr + i);
        float4 wa = *(const float4*)(wr + i);
        float4 wb = *(const float4*)(wr + i + 4);
        sum += bf2f((unsigned short)hv[0]) * wa.x;
        sum += bf2f((unsigned short)hv[1]) * wa.y;
        sum += bf2f((unsigned short)hv[2]) * wa.z;
        sum += bf2f((unsigned short)hv[3]) * wa.w;
        sum += bf2f((unsigned short)hv[4]) * wb.x;
        sum += bf2f((unsigned short)hv[5]) * wb.y;
        sum += bf2f((unsigned short)hv[6]) * wb.z;
        sum += bf2f((unsigned short)hv[7]) * wb.w;
    }
    sum += __shfl_xor(sum, 16);
    sum += __shfl_xor(sum, 32);
    if (kc == 0) {
        float qv = sum + bq[a];
        int av = avail[row * 16 + a];
        if (av == 0) qv -= 1e10f;
        qout[row * 16 + a] = qv;
    }
}

// ---------------------------------------------------------------------------
extern "C" void kernel_launch(void* const* d_in, const int* in_sizes, int n_in,
                              void* d_out, int out_size, void* d_ws, size_t ws_size,
                              hipStream_t stream)
{
    const float* hidden = (const float*)d_in[0];
    const float* x      = (const float*)d_in[1];
    const int*   dones  = (const int*)d_in[2];
    const int*   avail  = (const int*)d_in[3];
    const float* Wl     = (const float*)d_in[4];
    const float* bl     = (const float*)d_in[5];
    const float* ln_g   = (const float*)d_in[6];
    const float* ln_b   = (const float*)d_in[7];
    const float* W_ih   = (const float*)d_in[8];
    const float* W_hh   = (const float*)d_in[9];
    const float* b_ih   = (const float*)d_in[10];
    const float* b_hh   = (const float*)d_in[11];
    const float* Wq     = (const float*)d_in[12];
    const float* bq     = (const float*)d_in[13];

    char* p = (char*)d_ws;
    unsigned short* gi   = (unsigned short*)p; p += (size_t)NROWS * 1536 * 2;   // 48 MB
    unsigned short* rnn  = (unsigned short*)p; p += (size_t)NROWS * H * 2;      // 16 MB
    unsigned short* hst0 = (unsigned short*)p; p += (size_t)HSTCAP * H * 2;     // 12 MB
    unsigned short* hst1 = (unsigned short*)p; p += (size_t)HSTCAP * H * 2;     // 12 MB
    unsigned short* wlb  = (unsigned short*)p; p += (size_t)4 * H * H * 2;      // 2 MB
    unsigned short* wihb = (unsigned short*)p; p += (size_t)3 * H * H * 2;      // 1.5 MB
    int* lenArr = (int*)p;          p += (size_t)NROWS * 4;   // 64 KB
    int* recs   = (int*)p;          p += (size_t)NROWS * 4;   // 64 KB
    int* pmap   = (int*)p;          p += (size_t)NROWS * 4;   // 64 KB
    unsigned int* meta = (unsigned int*)p;  p += 12288;
    unsigned int* hist = meta + 1024;
    unsigned int* offs = meta + 1296;
    int* Marr = (int*)(meta + 1568);
    unsigned int* ssum = meta + 1840;

    // 1) weights -> bf16; zero meta (incl. 16 domain barrier slots)
    cvt_init<<<1792, 256, 0, stream>>>(Wl, W_ih, wlb, wihb, meta);

    // 2) segment machinery
    seg_build<<<64, 256, 0, stream>>>(dones, lenArr, hist);
    seg_offsets<<<1, 256, 0, stream>>>(hist, Marr, offs, ssum);
    seg_scatter<<<64, 256, 0, stream>>>(lenArr, offs, recs);
    pmap_build<<<64, 256, 0, stream>>>(recs, Marr, ssum, lenArr, pmap);

    // 3) init h_state rows by rank (independent of MLP now)
    h_init<<<HSTCAP / 4, 256, 0, stream>>>(recs, Marr, dones, hidden, hst0);

    // 4) fused x->MLPx4->gi (row-local, one launch)
    mlp_gi<<<256, 256, 0, stream>>>(x, wlb, wihb, bl, ln_g, ln_b, b_ih, pmap, gi);

    // 5) segment-parallel GRU scan (16 domains x 16 WGs, relaxed barriers)
    gru_seg_scan<<<256, 256, 0, stream>>>(gi, W_hh, b_hh, Marr, ssum, recs,
                                          hst0, hst1, rnn, (float*)d_out, meta);

    // 6) Q head + availability mask
    qhead<<<4096, 256, 0, stream>>>(rnn, Wq, bq, avail, (float*)d_out + BATCH * H);
}